// Round 1
// baseline (565.423 us; speedup 1.0000x reference)
//
#include <hip/hip_runtime.h>
#include <hip/hip_bf16.h>

#define N_NODES 50000
#define E_EDGES 600000
#define F_IN    256
#define HC1     128   // 4 heads * 32
#define F_OUT   64

// -------------------- CSR build --------------------

__global__ void hist_kernel(const int* __restrict__ ei, int* __restrict__ count) {
    int i = blockIdx.x * blockDim.x + threadIdx.x;
    const int total = E_EDGES + N_NODES;
    if (i >= total) return;
    int d = (i < E_EDGES) ? ei[E_EDGES + i] : (i - E_EDGES);
    atomicAdd(&count[d], 1);
}

__global__ __launch_bounds__(1024) void scan_kernel(int* __restrict__ cursor /*in counts, out offsets*/,
                                                    int* __restrict__ row_ptr) {
    __shared__ int wsum[16];
    __shared__ int running_s;
    int tid = threadIdx.x, lane = tid & 63, w = tid >> 6;
    if (tid == 0) running_s = 0;
    __syncthreads();
    for (int base = 0; base < N_NODES; base += 1024) {
        int i = base + tid;
        int v = (i < N_NODES) ? cursor[i] : 0;
        int s = v;
        #pragma unroll
        for (int d = 1; d < 64; d <<= 1) {
            int t = __shfl_up(s, d);
            if (lane >= d) s += t;
        }
        if (lane == 63) wsum[w] = s;
        __syncthreads();
        if (tid < 16) {
            int ws = wsum[tid];
            #pragma unroll
            for (int d = 1; d < 16; d <<= 1) {
                int t = __shfl_up(ws, d);
                if (tid >= d) ws += t;
            }
            wsum[tid] = ws;  // inclusive scan of wave sums
        }
        __syncthreads();
        int run = running_s;
        int excl = run + (w ? wsum[w - 1] : 0) + s - v;
        if (i < N_NODES) { row_ptr[i] = excl; cursor[i] = excl; }
        int total = wsum[15];
        __syncthreads();   // everyone done reading running_s/wsum
        if (tid == 0) running_s = run + total;
        __syncthreads();
    }
    if (threadIdx.x == 0) row_ptr[N_NODES] = running_s;
}

__global__ void scatter_kernel(const int* __restrict__ ei, int* __restrict__ cursor,
                               int* __restrict__ esrc) {
    int i = blockIdx.x * blockDim.x + threadIdx.x;
    const int total = E_EDGES + N_NODES;
    if (i >= total) return;
    int s, d;
    if (i < E_EDGES) { s = ei[i]; d = ei[E_EDGES + i]; }
    else             { s = d = i - E_EDGES; }
    int pos = atomicAdd(&cursor[d], 1);
    esrc[pos] = s;
}

// -------------------- GEMMs (fp32) --------------------

// h1 = x @ W1 : [N,256]x[256,128]. 16 rows/block, 256 thr = 128 cols x 2 rowpair.
__global__ __launch_bounds__(256) void gemm1_kernel(const float* __restrict__ x,
                                                    const float* __restrict__ W,
                                                    float* __restrict__ h1) {
    __shared__ float xs[16][F_IN];
    int r0 = blockIdx.x * 16;
    int tid = threadIdx.x;
    const float4* xg = (const float4*)(x + (size_t)r0 * F_IN);
    float4* xs4 = (float4*)&xs[0][0];
    #pragma unroll
    for (int j = 0; j < 4; ++j) xs4[tid + 256 * j] = xg[tid + 256 * j];
    __syncthreads();
    int col = tid & 127;
    int rp  = tid >> 7;   // 0..1, rows rp, rp+2, ..., rp+14
    float acc[8] = {0,0,0,0,0,0,0,0};
    for (int k = 0; k < F_IN; k += 4) {
        float w0 = W[(k + 0) * HC1 + col];
        float w1 = W[(k + 1) * HC1 + col];
        float w2 = W[(k + 2) * HC1 + col];
        float w3 = W[(k + 3) * HC1 + col];
        #pragma unroll
        for (int j = 0; j < 8; ++j) {
            float4 xv = *(const float4*)&xs[rp + 2 * j][k];
            acc[j] += xv.x * w0 + xv.y * w1 + xv.z * w2 + xv.w * w3;
        }
    }
    #pragma unroll
    for (int j = 0; j < 8; ++j)
        h1[(size_t)(r0 + rp + 2 * j) * HC1 + col] = acc[j];
}

// g = h2 @ W2 : [N,128]x[128,64]. 16 rows/block, 256 thr = 64 cols x 4 rowgroup.
__global__ __launch_bounds__(256) void gemm2_kernel(const float* __restrict__ h2,
                                                    const float* __restrict__ W,
                                                    float* __restrict__ g) {
    __shared__ float xs[16][HC1];
    int r0 = blockIdx.x * 16;
    int tid = threadIdx.x;
    const float4* xg = (const float4*)(h2 + (size_t)r0 * HC1);
    float4* xs4 = (float4*)&xs[0][0];
    #pragma unroll
    for (int j = 0; j < 2; ++j) xs4[tid + 256 * j] = xg[tid + 256 * j];
    __syncthreads();
    int col = tid & 63;
    int rp  = tid >> 6;   // 0..3, rows rp, rp+4, rp+8, rp+12
    float acc[4] = {0,0,0,0};
    for (int k = 0; k < HC1; k += 4) {
        float w0 = W[(k + 0) * F_OUT + col];
        float w1 = W[(k + 1) * F_OUT + col];
        float w2 = W[(k + 2) * F_OUT + col];
        float w3 = W[(k + 3) * F_OUT + col];
        #pragma unroll
        for (int j = 0; j < 4; ++j) {
            float4 xv = *(const float4*)&xs[rp + 4 * j][k];
            acc[j] += xv.x * w0 + xv.y * w1 + xv.z * w2 + xv.w * w3;
        }
    }
    #pragma unroll
    for (int j = 0; j < 4; ++j)
        g[(size_t)(r0 + rp + 4 * j) * F_OUT + col] = acc[j];
}

// -------------------- attention scalars --------------------

// al_s1[n][h] = dot(h1[n, h*32:(h+1)*32], a_src1[h]); same for dst. 1 wave/row.
__global__ __launch_bounds__(256) void al1_kernel(const float* __restrict__ h1,
                                                  const float* __restrict__ a_src,
                                                  const float* __restrict__ a_dst,
                                                  float* __restrict__ al_s,
                                                  float* __restrict__ al_d) {
    int wid = blockIdx.x * 4 + (threadIdx.x >> 6);
    int lane = threadIdx.x & 63;
    const float* hr = h1 + (size_t)wid * HC1;
    float v0 = hr[lane], v1 = hr[lane + 64];
    float s0 = v0 * a_src[lane], s1 = v1 * a_src[lane + 64];
    float d0 = v0 * a_dst[lane], d1 = v1 * a_dst[lane + 64];
    #pragma unroll
    for (int d = 1; d < 32; d <<= 1) {
        s0 += __shfl_xor(s0, d); s1 += __shfl_xor(s1, d);
        d0 += __shfl_xor(d0, d); d1 += __shfl_xor(d1, d);
    }
    if ((lane & 31) == 0) {
        int h = lane >> 5;  // 0 or 1
        al_s[wid * 4 + h] = s0;     al_s[wid * 4 + 2 + h] = s1;
        al_d[wid * 4 + h] = d0;     al_d[wid * 4 + 2 + h] = d1;
    }
}

// al_s2[n] = dot(g[n], a_src2); 1 wave/row.
__global__ __launch_bounds__(256) void al2_kernel(const float* __restrict__ g,
                                                  const float* __restrict__ a_src,
                                                  const float* __restrict__ a_dst,
                                                  float* __restrict__ al_s,
                                                  float* __restrict__ al_d) {
    int wid = blockIdx.x * 4 + (threadIdx.x >> 6);
    int lane = threadIdx.x & 63;
    float v = g[(size_t)wid * F_OUT + lane];
    float s = v * a_src[lane];
    float d = v * a_dst[lane];
    #pragma unroll
    for (int dd = 1; dd < 64; dd <<= 1) {
        s += __shfl_xor(s, dd);
        d += __shfl_xor(d, dd);
    }
    if (lane == 0) { al_s[wid] = s; al_d[wid] = d; }
}

__device__ __forceinline__ float lrelu(float x) { return x > 0.f ? x : 0.2f * x; }

// -------------------- per-dst softmax + aggregation --------------------

// layer 1: 1 wave per dst node, lane covers cols lane & lane+64 (heads lane>>5, 2+(lane>>5))
__global__ __launch_bounds__(256) void aggr1_kernel(const int* __restrict__ row_ptr,
                                                    const int* __restrict__ esrc,
                                                    const float* __restrict__ al_s,
                                                    const float* __restrict__ al_d,
                                                    const float* __restrict__ h1,
                                                    const float* __restrict__ b1,
                                                    float* __restrict__ h2out) {
    int wid = blockIdx.x * 4 + (threadIdx.x >> 6);
    int lane = threadIdx.x & 63;
    int beg = row_ptr[wid], end = row_ptr[wid + 1];
    int col0 = lane, col1 = lane + 64;
    int ha = col0 >> 5, hb = col1 >> 5;
    float ad0 = al_d[wid * 4 + ha], ad1 = al_d[wid * 4 + hb];
    // pass 1: max
    float m0 = -1e30f, m1 = -1e30f;
    for (int j = beg; j < end; ++j) {
        int s = esrc[j];
        float e0 = lrelu(al_s[s * 4 + ha] + ad0);
        float e1 = lrelu(al_s[s * 4 + hb] + ad1);
        m0 = fmaxf(m0, e0); m1 = fmaxf(m1, e1);
    }
    // pass 2: sum exp
    float S0 = 0.f, S1 = 0.f;
    for (int j = beg; j < end; ++j) {
        int s = esrc[j];
        float e0 = lrelu(al_s[s * 4 + ha] + ad0);
        float e1 = lrelu(al_s[s * 4 + hb] + ad1);
        S0 += __expf(e0 - m0); S1 += __expf(e1 - m1);
    }
    float inv0 = 1.f / S0, inv1 = 1.f / S1;
    // pass 3: aggregate
    float acc0 = 0.f, acc1 = 0.f;
    for (int j = beg; j < end; ++j) {
        int s = esrc[j];
        float e0 = lrelu(al_s[s * 4 + ha] + ad0);
        float e1 = lrelu(al_s[s * 4 + hb] + ad1);
        float a0 = __expf(e0 - m0) * inv0;
        float a1 = __expf(e1 - m1) * inv1;
        const float* hrow = h1 + (size_t)s * HC1;
        acc0 += a0 * hrow[col0];
        acc1 += a1 * hrow[col1];
    }
    float o0 = lrelu(acc0 + b1[col0]);
    float o1 = lrelu(acc1 + b1[col1]);
    float* orow = h2out + (size_t)wid * HC1;
    orow[col0] = o0;
    orow[col1] = o1;
}

// layer 2: 1 wave per dst node, 1 head, 64 cols
__global__ __launch_bounds__(256) void aggr2_kernel(const int* __restrict__ row_ptr,
                                                    const int* __restrict__ esrc,
                                                    const float* __restrict__ al_s,
                                                    const float* __restrict__ al_d,
                                                    const float* __restrict__ g,
                                                    const float* __restrict__ b2,
                                                    float* __restrict__ out) {
    int wid = blockIdx.x * 4 + (threadIdx.x >> 6);
    int lane = threadIdx.x & 63;
    int beg = row_ptr[wid], end = row_ptr[wid + 1];
    float ad = al_d[wid];
    float m = -1e30f;
    for (int j = beg; j < end; ++j) {
        float e = lrelu(al_s[esrc[j]] + ad);
        m = fmaxf(m, e);
    }
    float S = 0.f;
    for (int j = beg; j < end; ++j) {
        float e = lrelu(al_s[esrc[j]] + ad);
        S += __expf(e - m);
    }
    float inv = 1.f / S;
    float acc = 0.f;
    for (int j = beg; j < end; ++j) {
        int s = esrc[j];
        float e = lrelu(al_s[s] + ad);
        float a = __expf(e - m) * inv;
        acc += a * g[(size_t)s * F_OUT + lane];
    }
    out[(size_t)wid * F_OUT + lane] = acc + b2[lane];
}

// -------------------- launch --------------------

extern "C" void kernel_launch(void* const* d_in, const int* in_sizes, int n_in,
                              void* d_out, int out_size, void* d_ws, size_t ws_size,
                              hipStream_t stream) {
    const float* x      = (const float*)d_in[0];
    const int*   ei     = (const int*)  d_in[1];
    const float* W1     = (const float*)d_in[2];
    const float* a_src1 = (const float*)d_in[3];
    const float* a_dst1 = (const float*)d_in[4];
    const float* b1     = (const float*)d_in[5];
    const float* W2     = (const float*)d_in[6];
    const float* a_src2 = (const float*)d_in[7];
    const float* a_dst2 = (const float*)d_in[8];
    const float* b2     = (const float*)d_in[9];
    float* out = (float*)d_out;
    char* ws = (char*)d_ws;

    // workspace layout (bytes)
    float* h1    = (float*)(ws + 0);            // N*128*4 = 25,600,000
    float* h2    = (float*)(ws + 25600000);     // N*128*4
    float* g     = (float*)(ws + 51200000);     // N*64*4 = 12,800,000
    float* als1  = (float*)(ws + 64000000);     // N*4*4
    float* ald1  = (float*)(ws + 64800000);     // N*4*4
    float* als2  = (float*)(ws + 65600000);     // N*4
    float* ald2  = (float*)(ws + 65800000);     // N*4
    int*   rowp  = (int*)  (ws + 66000000);     // (N+1)*4
    int*   cursor= (int*)  (ws + 66200320);     // N*4
    int*   esrc  = (int*)  (ws + 66400320);     // (E+N)*4 = 2,600,000

    const int TOT = E_EDGES + N_NODES;
    const int eb = (TOT + 255) / 256;

    hipMemsetAsync(cursor, 0, N_NODES * sizeof(int), stream);
    hist_kernel<<<eb, 256, 0, stream>>>(ei, cursor);
    scan_kernel<<<1, 1024, 0, stream>>>(cursor, rowp);
    scatter_kernel<<<eb, 256, 0, stream>>>(ei, cursor, esrc);

    gemm1_kernel<<<N_NODES / 16, 256, 0, stream>>>(x, W1, h1);
    al1_kernel<<<N_NODES / 4, 256, 0, stream>>>(h1, a_src1, a_dst1, als1, ald1);
    aggr1_kernel<<<N_NODES / 4, 256, 0, stream>>>(rowp, esrc, als1, ald1, h1, b1, h2);

    gemm2_kernel<<<N_NODES / 16, 256, 0, stream>>>(h2, W2, g);
    al2_kernel<<<N_NODES / 4, 256, 0, stream>>>(g, a_src2, a_dst2, als2, ald2);
    aggr2_kernel<<<N_NODES / 4, 256, 0, stream>>>(rowp, esrc, als2, ald2, g, b2, out);
}

// Round 2
// 376.223 us; speedup vs baseline: 1.5029x; 1.5029x over previous
//
#include <hip/hip_runtime.h>
#include <hip/hip_bf16.h>

#define N_NODES 50000
#define E_EDGES 600000
#define F_IN    256
#define HC1     128   // 4 heads * 32
#define F_OUT   64

// -------------------- CSR build --------------------

__global__ void hist_kernel(const int* __restrict__ ei, int* __restrict__ count) {
    int i = blockIdx.x * blockDim.x + threadIdx.x;
    const int total = E_EDGES + N_NODES;
    if (i >= total) return;
    int d = (i < E_EDGES) ? ei[E_EDGES + i] : (i - E_EDGES);
    atomicAdd(&count[d], 1);
}

__global__ __launch_bounds__(1024) void scan_kernel(int* __restrict__ cursor /*in counts, out offsets*/,
                                                    int* __restrict__ row_ptr) {
    __shared__ int wsum[16];
    __shared__ int running_s;
    int tid = threadIdx.x, lane = tid & 63, w = tid >> 6;
    if (tid == 0) running_s = 0;
    __syncthreads();
    for (int base = 0; base < N_NODES; base += 1024) {
        int i = base + tid;
        int v = (i < N_NODES) ? cursor[i] : 0;
        int s = v;
        #pragma unroll
        for (int d = 1; d < 64; d <<= 1) {
            int t = __shfl_up(s, d);
            if (lane >= d) s += t;
        }
        if (lane == 63) wsum[w] = s;
        __syncthreads();
        if (tid < 16) {
            int ws = wsum[tid];
            #pragma unroll
            for (int d = 1; d < 16; d <<= 1) {
                int t = __shfl_up(ws, d);
                if (tid >= d) ws += t;
            }
            wsum[tid] = ws;  // inclusive scan of wave sums
        }
        __syncthreads();
        int run = running_s;
        int excl = run + (w ? wsum[w - 1] : 0) + s - v;
        if (i < N_NODES) { row_ptr[i] = excl; cursor[i] = excl; }
        int total = wsum[15];
        __syncthreads();   // everyone done reading running_s/wsum
        if (tid == 0) running_s = run + total;
        __syncthreads();
    }
    if (threadIdx.x == 0) row_ptr[N_NODES] = running_s;
}

__global__ void scatter_kernel(const int* __restrict__ ei, int* __restrict__ cursor,
                               int* __restrict__ esrc) {
    int i = blockIdx.x * blockDim.x + threadIdx.x;
    const int total = E_EDGES + N_NODES;
    if (i >= total) return;
    int s, d;
    if (i < E_EDGES) { s = ei[i]; d = ei[E_EDGES + i]; }
    else             { s = d = i - E_EDGES; }
    int pos = atomicAdd(&cursor[d], 1);
    esrc[pos] = s;
}

// -------------------- GEMMs (fp32) --------------------

// h1 = x @ W1 : [N,256]x[256,128]. 16 rows/block, 256 thr = 128 cols x 2 rowpair.
__global__ __launch_bounds__(256) void gemm1_kernel(const float* __restrict__ x,
                                                    const float* __restrict__ W,
                                                    float* __restrict__ h1) {
    __shared__ float xs[16][F_IN];
    int r0 = blockIdx.x * 16;
    int tid = threadIdx.x;
    const float4* xg = (const float4*)(x + (size_t)r0 * F_IN);
    float4* xs4 = (float4*)&xs[0][0];
    #pragma unroll
    for (int j = 0; j < 4; ++j) xs4[tid + 256 * j] = xg[tid + 256 * j];
    __syncthreads();
    int col = tid & 127;
    int rp  = tid >> 7;   // 0..1, rows rp, rp+2, ..., rp+14
    float acc[8] = {0,0,0,0,0,0,0,0};
    for (int k = 0; k < F_IN; k += 4) {
        float w0 = W[(k + 0) * HC1 + col];
        float w1 = W[(k + 1) * HC1 + col];
        float w2 = W[(k + 2) * HC1 + col];
        float w3 = W[(k + 3) * HC1 + col];
        #pragma unroll
        for (int j = 0; j < 8; ++j) {
            float4 xv = *(const float4*)&xs[rp + 2 * j][k];
            acc[j] += xv.x * w0 + xv.y * w1 + xv.z * w2 + xv.w * w3;
        }
    }
    #pragma unroll
    for (int j = 0; j < 8; ++j)
        h1[(size_t)(r0 + rp + 2 * j) * HC1 + col] = acc[j];
}

// g = h2 @ W2 : [N,128]x[128,64]. 16 rows/block, 256 thr = 64 cols x 4 rowgroup.
__global__ __launch_bounds__(256) void gemm2_kernel(const float* __restrict__ h2,
                                                    const float* __restrict__ W,
                                                    float* __restrict__ g) {
    __shared__ float xs[16][HC1];
    int r0 = blockIdx.x * 16;
    int tid = threadIdx.x;
    const float4* xg = (const float4*)(h2 + (size_t)r0 * HC1);
    float4* xs4 = (float4*)&xs[0][0];
    #pragma unroll
    for (int j = 0; j < 2; ++j) xs4[tid + 256 * j] = xg[tid + 256 * j];
    __syncthreads();
    int col = tid & 63;
    int rp  = tid >> 6;   // 0..3, rows rp, rp+4, rp+8, rp+12
    float acc[4] = {0,0,0,0};
    for (int k = 0; k < HC1; k += 4) {
        float w0 = W[(k + 0) * F_OUT + col];
        float w1 = W[(k + 1) * F_OUT + col];
        float w2 = W[(k + 2) * F_OUT + col];
        float w3 = W[(k + 3) * F_OUT + col];
        #pragma unroll
        for (int j = 0; j < 4; ++j) {
            float4 xv = *(const float4*)&xs[rp + 4 * j][k];
            acc[j] += xv.x * w0 + xv.y * w1 + xv.z * w2 + xv.w * w3;
        }
    }
    #pragma unroll
    for (int j = 0; j < 4; ++j)
        g[(size_t)(r0 + rp + 4 * j) * F_OUT + col] = acc[j];
}

// -------------------- attention scalars --------------------

// al_s1[n][h] = dot(h1[n, h*32:(h+1)*32], a_src1[h]); same for dst. 1 wave/row.
__global__ __launch_bounds__(256) void al1_kernel(const float* __restrict__ h1,
                                                  const float* __restrict__ a_src,
                                                  const float* __restrict__ a_dst,
                                                  float* __restrict__ al_s,
                                                  float* __restrict__ al_d) {
    int wid = blockIdx.x * 4 + (threadIdx.x >> 6);
    int lane = threadIdx.x & 63;
    const float* hr = h1 + (size_t)wid * HC1;
    float v0 = hr[lane], v1 = hr[lane + 64];
    float s0 = v0 * a_src[lane], s1 = v1 * a_src[lane + 64];
    float d0 = v0 * a_dst[lane], d1 = v1 * a_dst[lane + 64];
    #pragma unroll
    for (int d = 1; d < 32; d <<= 1) {
        s0 += __shfl_xor(s0, d); s1 += __shfl_xor(s1, d);
        d0 += __shfl_xor(d0, d); d1 += __shfl_xor(d1, d);
    }
    if ((lane & 31) == 0) {
        int h = lane >> 5;  // 0 or 1
        al_s[wid * 4 + h] = s0;     al_s[wid * 4 + 2 + h] = s1;
        al_d[wid * 4 + h] = d0;     al_d[wid * 4 + 2 + h] = d1;
    }
}

// al_s2[n] = dot(g[n], a_src2); 1 wave/row.
__global__ __launch_bounds__(256) void al2_kernel(const float* __restrict__ g,
                                                  const float* __restrict__ a_src,
                                                  const float* __restrict__ a_dst,
                                                  float* __restrict__ al_s,
                                                  float* __restrict__ al_d) {
    int wid = blockIdx.x * 4 + (threadIdx.x >> 6);
    int lane = threadIdx.x & 63;
    float v = g[(size_t)wid * F_OUT + lane];
    float s = v * a_src[lane];
    float d = v * a_dst[lane];
    #pragma unroll
    for (int dd = 1; dd < 64; dd <<= 1) {
        s += __shfl_xor(s, dd);
        d += __shfl_xor(d, dd);
    }
    if (lane == 0) { al_s[wid] = s; al_d[wid] = d; }
}

__device__ __forceinline__ float lrelu(float x) { return x > 0.f ? x : 0.2f * x; }

// -------------------- attention coefficients (edge-parallel per dst) --------------------

// layer 1: one wave per dst; lanes stride over incoming edges; 4 heads per lane.
// Writes normalized alpha[(E+N)][4] in CSR order.
__global__ __launch_bounds__(256) void alpha1_kernel(const int* __restrict__ row_ptr,
                                                     const int* __restrict__ esrc,
                                                     const float* __restrict__ al_s,
                                                     const float* __restrict__ al_d,
                                                     float* __restrict__ alpha) {
    int wid = blockIdx.x * 4 + (threadIdx.x >> 6);
    int lane = threadIdx.x & 63;
    int beg = row_ptr[wid], end = row_ptr[wid + 1];
    const float4 ad = *(const float4*)&al_d[wid * 4];
    float m0 = -1e30f, m1 = -1e30f, m2 = -1e30f, m3 = -1e30f;
    for (int j = beg + lane; j < end; j += 64) {
        int s = esrc[j];
        float4 as = *(const float4*)&al_s[s * 4];
        float e0 = lrelu(as.x + ad.x), e1 = lrelu(as.y + ad.y);
        float e2 = lrelu(as.z + ad.z), e3 = lrelu(as.w + ad.w);
        *(float4*)&alpha[(size_t)j * 4] = make_float4(e0, e1, e2, e3);
        m0 = fmaxf(m0, e0); m1 = fmaxf(m1, e1); m2 = fmaxf(m2, e2); m3 = fmaxf(m3, e3);
    }
    #pragma unroll
    for (int d = 1; d < 64; d <<= 1) {
        m0 = fmaxf(m0, __shfl_xor(m0, d)); m1 = fmaxf(m1, __shfl_xor(m1, d));
        m2 = fmaxf(m2, __shfl_xor(m2, d)); m3 = fmaxf(m3, __shfl_xor(m3, d));
    }
    float S0 = 0.f, S1 = 0.f, S2 = 0.f, S3 = 0.f;
    for (int j = beg + lane; j < end; j += 64) {
        float4 e = *(const float4*)&alpha[(size_t)j * 4];
        S0 += __expf(e.x - m0); S1 += __expf(e.y - m1);
        S2 += __expf(e.z - m2); S3 += __expf(e.w - m3);
    }
    #pragma unroll
    for (int d = 1; d < 64; d <<= 1) {
        S0 += __shfl_xor(S0, d); S1 += __shfl_xor(S1, d);
        S2 += __shfl_xor(S2, d); S3 += __shfl_xor(S3, d);
    }
    float i0 = 1.f / S0, i1 = 1.f / S1, i2 = 1.f / S2, i3 = 1.f / S3;
    for (int j = beg + lane; j < end; j += 64) {
        float4 e = *(const float4*)&alpha[(size_t)j * 4];
        *(float4*)&alpha[(size_t)j * 4] =
            make_float4(__expf(e.x - m0) * i0, __expf(e.y - m1) * i1,
                        __expf(e.z - m2) * i2, __expf(e.w - m3) * i3);
    }
}

// layer 2: one wave per dst; lanes stride over edges; 1 head.
__global__ __launch_bounds__(256) void alpha2_kernel(const int* __restrict__ row_ptr,
                                                     const int* __restrict__ esrc,
                                                     const float* __restrict__ al_s,
                                                     const float* __restrict__ al_d,
                                                     float* __restrict__ alpha) {
    int wid = blockIdx.x * 4 + (threadIdx.x >> 6);
    int lane = threadIdx.x & 63;
    int beg = row_ptr[wid], end = row_ptr[wid + 1];
    const float ad = al_d[wid];
    float m = -1e30f;
    for (int j = beg + lane; j < end; j += 64) {
        float e = lrelu(al_s[esrc[j]] + ad);
        alpha[j] = e;
        m = fmaxf(m, e);
    }
    #pragma unroll
    for (int d = 1; d < 64; d <<= 1) m = fmaxf(m, __shfl_xor(m, d));
    float S = 0.f;
    for (int j = beg + lane; j < end; j += 64) S += __expf(alpha[j] - m);
    #pragma unroll
    for (int d = 1; d < 64; d <<= 1) S += __shfl_xor(S, d);
    float inv = 1.f / S;
    for (int j = beg + lane; j < end; j += 64)
        alpha[j] = __expf(alpha[j] - m) * inv;
}

// -------------------- aggregation (single pass, no exp) --------------------

// layer 1: 1 wave per dst node, lane covers cols lane & lane+64.
__global__ __launch_bounds__(256) void aggr1_kernel(const int* __restrict__ row_ptr,
                                                    const int* __restrict__ esrc,
                                                    const float* __restrict__ alpha,
                                                    const float* __restrict__ h1,
                                                    const float* __restrict__ b1,
                                                    float* __restrict__ h2out) {
    int wid = blockIdx.x * 4 + (threadIdx.x >> 6);
    int lane = threadIdx.x & 63;
    int beg = row_ptr[wid], end = row_ptr[wid + 1];
    int ha = lane >> 5;     // head index within first pair (0/1); +2 for second
    float acc0 = 0.f, acc1 = 0.f;
    int j = beg;
    for (; j + 2 <= end; j += 2) {
        int s0 = esrc[j], s1 = esrc[j + 1];
        float a00 = alpha[(size_t)j * 4 + ha],       a01 = alpha[(size_t)j * 4 + 2 + ha];
        float a10 = alpha[(size_t)(j + 1) * 4 + ha], a11 = alpha[(size_t)(j + 1) * 4 + 2 + ha];
        const float* r0 = h1 + (size_t)s0 * HC1;
        const float* r1 = h1 + (size_t)s1 * HC1;
        float h00 = r0[lane], h01 = r0[lane + 64];
        float h10 = r1[lane], h11 = r1[lane + 64];
        acc0 += a00 * h00 + a10 * h10;
        acc1 += a01 * h01 + a11 * h11;
    }
    if (j < end) {
        int s0 = esrc[j];
        float a00 = alpha[(size_t)j * 4 + ha], a01 = alpha[(size_t)j * 4 + 2 + ha];
        const float* r0 = h1 + (size_t)s0 * HC1;
        acc0 += a00 * r0[lane];
        acc1 += a01 * r0[lane + 64];
    }
    float o0 = lrelu(acc0 + b1[lane]);
    float o1 = lrelu(acc1 + b1[lane + 64]);
    float* orow = h2out + (size_t)wid * HC1;
    orow[lane] = o0;
    orow[lane + 64] = o1;
}

// layer 2: 1 wave per dst node, 1 head, 64 cols.
__global__ __launch_bounds__(256) void aggr2_kernel(const int* __restrict__ row_ptr,
                                                    const int* __restrict__ esrc,
                                                    const float* __restrict__ alpha,
                                                    const float* __restrict__ g,
                                                    const float* __restrict__ b2,
                                                    float* __restrict__ out) {
    int wid = blockIdx.x * 4 + (threadIdx.x >> 6);
    int lane = threadIdx.x & 63;
    int beg = row_ptr[wid], end = row_ptr[wid + 1];
    float acc = 0.f;
    int j = beg;
    for (; j + 2 <= end; j += 2) {
        int s0 = esrc[j], s1 = esrc[j + 1];
        float a0 = alpha[j], a1 = alpha[j + 1];
        float g0 = g[(size_t)s0 * F_OUT + lane];
        float g1 = g[(size_t)s1 * F_OUT + lane];
        acc += a0 * g0 + a1 * g1;
    }
    if (j < end) {
        acc += alpha[j] * g[(size_t)esrc[j] * F_OUT + lane];
    }
    out[(size_t)wid * F_OUT + lane] = acc + b2[lane];
}

// -------------------- launch --------------------

extern "C" void kernel_launch(void* const* d_in, const int* in_sizes, int n_in,
                              void* d_out, int out_size, void* d_ws, size_t ws_size,
                              hipStream_t stream) {
    const float* x      = (const float*)d_in[0];
    const int*   ei     = (const int*)  d_in[1];
    const float* W1     = (const float*)d_in[2];
    const float* a_src1 = (const float*)d_in[3];
    const float* a_dst1 = (const float*)d_in[4];
    const float* b1     = (const float*)d_in[5];
    const float* W2     = (const float*)d_in[6];
    const float* a_src2 = (const float*)d_in[7];
    const float* a_dst2 = (const float*)d_in[8];
    const float* b2     = (const float*)d_in[9];
    float* out = (float*)d_out;
    char* ws = (char*)d_ws;

    // workspace layout (bytes)
    float* h1    = (float*)(ws + 0);            // N*128*4 = 25,600,000
    float* h2    = (float*)(ws + 25600000);     // N*128*4
    float* g     = (float*)(ws + 51200000);     // N*64*4 = 12,800,000
    float* als1  = (float*)(ws + 64000000);     // N*4*4
    float* ald1  = (float*)(ws + 64800000);     // N*4*4
    float* als2  = (float*)(ws + 65600000);     // N*4
    float* ald2  = (float*)(ws + 65800000);     // N*4
    int*   rowp  = (int*)  (ws + 66000000);     // (N+1)*4
    int*   cursor= (int*)  (ws + 66200320);     // N*4
    int*   esrc  = (int*)  (ws + 66400320);     // (E+N)*4 = 2,600,000
    // recycled regions:
    float* alphaA = g;                          // (E+N)*4 floats = 10.4MB <= 12.8MB; consumed before gemm2 writes g
    float* alphaB = h1;                         // (E+N) floats; h1 free after aggr1

    const int TOT = E_EDGES + N_NODES;
    const int eb = (TOT + 255) / 256;

    hipMemsetAsync(cursor, 0, N_NODES * sizeof(int), stream);
    hist_kernel<<<eb, 256, 0, stream>>>(ei, cursor);
    scan_kernel<<<1, 1024, 0, stream>>>(cursor, rowp);
    scatter_kernel<<<eb, 256, 0, stream>>>(ei, cursor, esrc);

    gemm1_kernel<<<N_NODES / 16, 256, 0, stream>>>(x, W1, h1);
    al1_kernel<<<N_NODES / 4, 256, 0, stream>>>(h1, a_src1, a_dst1, als1, ald1);
    alpha1_kernel<<<N_NODES / 4, 256, 0, stream>>>(rowp, esrc, als1, ald1, alphaA);
    aggr1_kernel<<<N_NODES / 4, 256, 0, stream>>>(rowp, esrc, alphaA, h1, b1, h2);

    gemm2_kernel<<<N_NODES / 16, 256, 0, stream>>>(h2, W2, g);
    al2_kernel<<<N_NODES / 4, 256, 0, stream>>>(g, a_src2, a_dst2, als2, ald2);
    alpha2_kernel<<<N_NODES / 4, 256, 0, stream>>>(rowp, esrc, als2, ald2, alphaB);
    aggr2_kernel<<<N_NODES / 4, 256, 0, stream>>>(rowp, esrc, alphaB, g, b2, out);
}

// Round 3
// 331.062 us; speedup vs baseline: 1.7079x; 1.1364x over previous
//
#include <hip/hip_runtime.h>
#include <hip/hip_bf16.h>

#define N_NODES 50000
#define E_EDGES 600000
#define F_IN    256
#define HC1     128   // 4 heads * 32
#define F_OUT   64

typedef __bf16 bf16x8 __attribute__((ext_vector_type(8)));
typedef float  f32x4  __attribute__((ext_vector_type(4)));

// -------------------- CSR build --------------------

__global__ void hist_kernel(const int* __restrict__ ei, int* __restrict__ count) {
    int i = blockIdx.x * blockDim.x + threadIdx.x;
    const int total = E_EDGES + N_NODES;
    if (i >= total) return;
    int d = (i < E_EDGES) ? ei[E_EDGES + i] : (i - E_EDGES);
    atomicAdd(&count[d], 1);
}

__global__ __launch_bounds__(1024) void scan_kernel(int* __restrict__ cursor /*in counts, out offsets*/,
                                                    int* __restrict__ row_ptr) {
    __shared__ int wsum[16];
    __shared__ int running_s;
    int tid = threadIdx.x, lane = tid & 63, w = tid >> 6;
    if (tid == 0) running_s = 0;
    __syncthreads();
    for (int base = 0; base < N_NODES; base += 1024) {
        int i = base + tid;
        int v = (i < N_NODES) ? cursor[i] : 0;
        int s = v;
        #pragma unroll
        for (int d = 1; d < 64; d <<= 1) {
            int t = __shfl_up(s, d);
            if (lane >= d) s += t;
        }
        if (lane == 63) wsum[w] = s;
        __syncthreads();
        if (tid < 16) {
            int ws = wsum[tid];
            #pragma unroll
            for (int d = 1; d < 16; d <<= 1) {
                int t = __shfl_up(ws, d);
                if (tid >= d) ws += t;
            }
            wsum[tid] = ws;  // inclusive scan of wave sums
        }
        __syncthreads();
        int run = running_s;
        int excl = run + (w ? wsum[w - 1] : 0) + s - v;
        if (i < N_NODES) { row_ptr[i] = excl; cursor[i] = excl; }
        int total = wsum[15];
        __syncthreads();   // everyone done reading running_s/wsum
        if (tid == 0) running_s = run + total;
        __syncthreads();
    }
    if (threadIdx.x == 0) row_ptr[N_NODES] = running_s;
}

__global__ void scatter_kernel(const int* __restrict__ ei, int* __restrict__ cursor,
                               int* __restrict__ esrc) {
    int i = blockIdx.x * blockDim.x + threadIdx.x;
    const int total = E_EDGES + N_NODES;
    if (i >= total) return;
    int s, d;
    if (i < E_EDGES) { s = ei[i]; d = ei[E_EDGES + i]; }
    else             { s = d = i - E_EDGES; }
    int pos = atomicAdd(&cursor[d], 1);
    esrc[pos] = s;
}

// -------------------- W pre-pack into MFMA B-fragment order (bf16 hi/lo) ------

// B-frag for 16x16x32: lane l holds k=(l>>4)*8+j, col=l&15 of each [32][16] tile.
// Packed index: ((ct*KT + kt)*64 + l)*8 + j.
template<int KDIM, int NC>
__global__ void pack_w_kernel(const float* __restrict__ W,
                              __bf16* __restrict__ hi, __bf16* __restrict__ lo) {
    constexpr int KT  = KDIM / 32;
    constexpr int LKT = (KT == 8) ? 3 : 2;
    int tid = blockIdx.x * blockDim.x + threadIdx.x;
    if (tid >= KDIM * NC) return;
    int j  = tid & 7;
    int l  = (tid >> 3) & 63;
    int kt = (tid >> 9) & (KT - 1);
    int ct = tid >> (9 + LKT);
    int k   = kt * 32 + (l >> 4) * 8 + j;
    int col = ct * 16 + (l & 15);
    float v = W[k * NC + col];
    __bf16 h = (__bf16)v;
    hi[tid] = h;
    lo[tid] = (__bf16)(v - (float)h);
}

// -------------------- split-bf16 MFMA GEMM --------------------
// C[M x NC] = A[M x KDIM] * W.  A is fp32, converted in-register to hi+lo bf16;
// product via 3 MFMAs (hi*hi + hi*lo + lo*hi), fp32 accumulate.
// Block: 4 waves x 16 rows = 64 rows. Wave computes 16 x NC.
template<int KDIM, int NC>
__global__ __launch_bounds__(256) void gemm_mfma_kernel(const float* __restrict__ A,
                                                        const __bf16* __restrict__ Whi,
                                                        const __bf16* __restrict__ Wlo,
                                                        float* __restrict__ C) {
    constexpr int KT = KDIM / 32;
    constexpr int CT = NC / 16;
    int tid = threadIdx.x;
    int w = tid >> 6, l = tid & 63;
    int r0 = blockIdx.x * 64 + w * 16;
    int arow = r0 + (l & 15);
    int arc = arow < N_NODES ? arow : N_NODES - 1;   // clamp loads; stores guarded
    int koff = (l >> 4) * 8;
    const float* ap = A + (size_t)arc * KDIM + koff;

    f32x4 acc[CT];
    #pragma unroll
    for (int c = 0; c < CT; ++c) acc[c] = (f32x4){0.f, 0.f, 0.f, 0.f};

    #pragma unroll
    for (int kt = 0; kt < KT; ++kt) {
        float4 x0 = *(const float4*)(ap + kt * 32);
        float4 x1 = *(const float4*)(ap + kt * 32 + 4);
        float xv[8] = {x0.x, x0.y, x0.z, x0.w, x1.x, x1.y, x1.z, x1.w};
        bf16x8 ahi, alo;
        #pragma unroll
        for (int j = 0; j < 8; ++j) {
            __bf16 h = (__bf16)xv[j];
            ahi[j] = h;
            alo[j] = (__bf16)(xv[j] - (float)h);
        }
        #pragma unroll
        for (int c = 0; c < CT; ++c) {
            size_t bidx = ((size_t)(c * KT + kt) * 64 + l) * 8;
            bf16x8 bhi = *(const bf16x8*)(Whi + bidx);
            bf16x8 blo = *(const bf16x8*)(Wlo + bidx);
            acc[c] = __builtin_amdgcn_mfma_f32_16x16x32_bf16(ahi, bhi, acc[c], 0, 0, 0);
            acc[c] = __builtin_amdgcn_mfma_f32_16x16x32_bf16(ahi, blo, acc[c], 0, 0, 0);
            acc[c] = __builtin_amdgcn_mfma_f32_16x16x32_bf16(alo, bhi, acc[c], 0, 0, 0);
        }
    }

    int crow0 = r0 + (l >> 4) * 4;
    int ccol = l & 15;
    #pragma unroll
    for (int c = 0; c < CT; ++c) {
        #pragma unroll
        for (int r = 0; r < 4; ++r) {
            int row = crow0 + r;
            if (row < N_NODES) C[(size_t)row * NC + c * 16 + ccol] = acc[c][r];
        }
    }
}

// -------------------- attention scalars --------------------

// al_s1[n][h] = dot(h1[n, h*32:(h+1)*32], a_src1[h]); same for dst. 1 wave/row.
__global__ __launch_bounds__(256) void al1_kernel(const float* __restrict__ h1,
                                                  const float* __restrict__ a_src,
                                                  const float* __restrict__ a_dst,
                                                  float* __restrict__ al_s,
                                                  float* __restrict__ al_d) {
    int wid = blockIdx.x * 4 + (threadIdx.x >> 6);
    int lane = threadIdx.x & 63;
    const float* hr = h1 + (size_t)wid * HC1;
    float v0 = hr[lane], v1 = hr[lane + 64];
    float s0 = v0 * a_src[lane], s1 = v1 * a_src[lane + 64];
    float d0 = v0 * a_dst[lane], d1 = v1 * a_dst[lane + 64];
    #pragma unroll
    for (int d = 1; d < 32; d <<= 1) {
        s0 += __shfl_xor(s0, d); s1 += __shfl_xor(s1, d);
        d0 += __shfl_xor(d0, d); d1 += __shfl_xor(d1, d);
    }
    if ((lane & 31) == 0) {
        int h = lane >> 5;  // 0 or 1
        al_s[wid * 4 + h] = s0;     al_s[wid * 4 + 2 + h] = s1;
        al_d[wid * 4 + h] = d0;     al_d[wid * 4 + 2 + h] = d1;
    }
}

// al_s2[n] = dot(g[n], a_src2); 1 wave/row.
__global__ __launch_bounds__(256) void al2_kernel(const float* __restrict__ g,
                                                  const float* __restrict__ a_src,
                                                  const float* __restrict__ a_dst,
                                                  float* __restrict__ al_s,
                                                  float* __restrict__ al_d) {
    int wid = blockIdx.x * 4 + (threadIdx.x >> 6);
    int lane = threadIdx.x & 63;
    float v = g[(size_t)wid * F_OUT + lane];
    float s = v * a_src[lane];
    float d = v * a_dst[lane];
    #pragma unroll
    for (int dd = 1; dd < 64; dd <<= 1) {
        s += __shfl_xor(s, dd);
        d += __shfl_xor(d, dd);
    }
    if (lane == 0) { al_s[wid] = s; al_d[wid] = d; }
}

__device__ __forceinline__ float lrelu(float x) { return x > 0.f ? x : 0.2f * x; }

// -------------------- attention coefficients (edge-parallel per dst) --------------------

__global__ __launch_bounds__(256) void alpha1_kernel(const int* __restrict__ row_ptr,
                                                     const int* __restrict__ esrc,
                                                     const float* __restrict__ al_s,
                                                     const float* __restrict__ al_d,
                                                     float* __restrict__ alpha) {
    int wid = blockIdx.x * 4 + (threadIdx.x >> 6);
    int lane = threadIdx.x & 63;
    int beg = row_ptr[wid], end = row_ptr[wid + 1];
    const float4 ad = *(const float4*)&al_d[wid * 4];
    float m0 = -1e30f, m1 = -1e30f, m2 = -1e30f, m3 = -1e30f;
    for (int j = beg + lane; j < end; j += 64) {
        int s = esrc[j];
        float4 as = *(const float4*)&al_s[s * 4];
        float e0 = lrelu(as.x + ad.x), e1 = lrelu(as.y + ad.y);
        float e2 = lrelu(as.z + ad.z), e3 = lrelu(as.w + ad.w);
        *(float4*)&alpha[(size_t)j * 4] = make_float4(e0, e1, e2, e3);
        m0 = fmaxf(m0, e0); m1 = fmaxf(m1, e1); m2 = fmaxf(m2, e2); m3 = fmaxf(m3, e3);
    }
    #pragma unroll
    for (int d = 1; d < 64; d <<= 1) {
        m0 = fmaxf(m0, __shfl_xor(m0, d)); m1 = fmaxf(m1, __shfl_xor(m1, d));
        m2 = fmaxf(m2, __shfl_xor(m2, d)); m3 = fmaxf(m3, __shfl_xor(m3, d));
    }
    float S0 = 0.f, S1 = 0.f, S2 = 0.f, S3 = 0.f;
    for (int j = beg + lane; j < end; j += 64) {
        float4 e = *(const float4*)&alpha[(size_t)j * 4];
        S0 += __expf(e.x - m0); S1 += __expf(e.y - m1);
        S2 += __expf(e.z - m2); S3 += __expf(e.w - m3);
    }
    #pragma unroll
    for (int d = 1; d < 64; d <<= 1) {
        S0 += __shfl_xor(S0, d); S1 += __shfl_xor(S1, d);
        S2 += __shfl_xor(S2, d); S3 += __shfl_xor(S3, d);
    }
    float i0 = 1.f / S0, i1 = 1.f / S1, i2 = 1.f / S2, i3 = 1.f / S3;
    for (int j = beg + lane; j < end; j += 64) {
        float4 e = *(const float4*)&alpha[(size_t)j * 4];
        *(float4*)&alpha[(size_t)j * 4] =
            make_float4(__expf(e.x - m0) * i0, __expf(e.y - m1) * i1,
                        __expf(e.z - m2) * i2, __expf(e.w - m3) * i3);
    }
}

__global__ __launch_bounds__(256) void alpha2_kernel(const int* __restrict__ row_ptr,
                                                     const int* __restrict__ esrc,
                                                     const float* __restrict__ al_s,
                                                     const float* __restrict__ al_d,
                                                     float* __restrict__ alpha) {
    int wid = blockIdx.x * 4 + (threadIdx.x >> 6);
    int lane = threadIdx.x & 63;
    int beg = row_ptr[wid], end = row_ptr[wid + 1];
    const float ad = al_d[wid];
    float m = -1e30f;
    for (int j = beg + lane; j < end; j += 64) {
        float e = lrelu(al_s[esrc[j]] + ad);
        alpha[j] = e;
        m = fmaxf(m, e);
    }
    #pragma unroll
    for (int d = 1; d < 64; d <<= 1) m = fmaxf(m, __shfl_xor(m, d));
    float S = 0.f;
    for (int j = beg + lane; j < end; j += 64) S += __expf(alpha[j] - m);
    #pragma unroll
    for (int d = 1; d < 64; d <<= 1) S += __shfl_xor(S, d);
    float inv = 1.f / S;
    for (int j = beg + lane; j < end; j += 64)
        alpha[j] = __expf(alpha[j] - m) * inv;
}

// -------------------- aggregation (single pass, no exp) --------------------

__global__ __launch_bounds__(256) void aggr1_kernel(const int* __restrict__ row_ptr,
                                                    const int* __restrict__ esrc,
                                                    const float* __restrict__ alpha,
                                                    const float* __restrict__ h1,
                                                    const float* __restrict__ b1,
                                                    float* __restrict__ h2out) {
    int wid = blockIdx.x * 4 + (threadIdx.x >> 6);
    int lane = threadIdx.x & 63;
    int beg = row_ptr[wid], end = row_ptr[wid + 1];
    int ha = lane >> 5;     // head index within first pair (0/1); +2 for second
    float acc0 = 0.f, acc1 = 0.f;
    int j = beg;
    for (; j + 2 <= end; j += 2) {
        int s0 = esrc[j], s1 = esrc[j + 1];
        float a00 = alpha[(size_t)j * 4 + ha],       a01 = alpha[(size_t)j * 4 + 2 + ha];
        float a10 = alpha[(size_t)(j + 1) * 4 + ha], a11 = alpha[(size_t)(j + 1) * 4 + 2 + ha];
        const float* r0 = h1 + (size_t)s0 * HC1;
        const float* r1 = h1 + (size_t)s1 * HC1;
        float h00 = r0[lane], h01 = r0[lane + 64];
        float h10 = r1[lane], h11 = r1[lane + 64];
        acc0 += a00 * h00 + a10 * h10;
        acc1 += a01 * h01 + a11 * h11;
    }
    if (j < end) {
        int s0 = esrc[j];
        float a00 = alpha[(size_t)j * 4 + ha], a01 = alpha[(size_t)j * 4 + 2 + ha];
        const float* r0 = h1 + (size_t)s0 * HC1;
        acc0 += a00 * r0[lane];
        acc1 += a01 * r0[lane + 64];
    }
    float o0 = lrelu(acc0 + b1[lane]);
    float o1 = lrelu(acc1 + b1[lane + 64]);
    float* orow = h2out + (size_t)wid * HC1;
    orow[lane] = o0;
    orow[lane + 64] = o1;
}

__global__ __launch_bounds__(256) void aggr2_kernel(const int* __restrict__ row_ptr,
                                                    const int* __restrict__ esrc,
                                                    const float* __restrict__ alpha,
                                                    const float* __restrict__ g,
                                                    const float* __restrict__ b2,
                                                    float* __restrict__ out) {
    int wid = blockIdx.x * 4 + (threadIdx.x >> 6);
    int lane = threadIdx.x & 63;
    int beg = row_ptr[wid], end = row_ptr[wid + 1];
    float acc = 0.f;
    int j = beg;
    for (; j + 2 <= end; j += 2) {
        int s0 = esrc[j], s1 = esrc[j + 1];
        float a0 = alpha[j], a1 = alpha[j + 1];
        float g0 = g[(size_t)s0 * F_OUT + lane];
        float g1 = g[(size_t)s1 * F_OUT + lane];
        acc += a0 * g0 + a1 * g1;
    }
    if (j < end) {
        acc += alpha[j] * g[(size_t)esrc[j] * F_OUT + lane];
    }
    out[(size_t)wid * F_OUT + lane] = acc + b2[lane];
}

// -------------------- launch --------------------

extern "C" void kernel_launch(void* const* d_in, const int* in_sizes, int n_in,
                              void* d_out, int out_size, void* d_ws, size_t ws_size,
                              hipStream_t stream) {
    const float* x      = (const float*)d_in[0];
    const int*   ei     = (const int*)  d_in[1];
    const float* W1     = (const float*)d_in[2];
    const float* a_src1 = (const float*)d_in[3];
    const float* a_dst1 = (const float*)d_in[4];
    const float* b1     = (const float*)d_in[5];
    const float* W2     = (const float*)d_in[6];
    const float* a_src2 = (const float*)d_in[7];
    const float* a_dst2 = (const float*)d_in[8];
    const float* b2     = (const float*)d_in[9];
    float* out = (float*)d_out;
    char* ws = (char*)d_ws;

    // workspace layout (bytes)
    float* h1    = (float*)(ws + 0);            // N*128*4 = 25,600,000
    float* h2    = (float*)(ws + 25600000);     // N*128*4
    float* g     = (float*)(ws + 51200000);     // N*64*4 = 12,800,000
    float* als1  = (float*)(ws + 64000000);     // N*4*4
    float* ald1  = (float*)(ws + 64800000);     // N*4*4
    float* als2  = (float*)(ws + 65600000);     // N*4
    float* ald2  = (float*)(ws + 65800000);     // N*4
    int*   rowp  = (int*)  (ws + 66000000);     // (N+1)*4
    int*   cursor= (int*)  (ws + 66200320);     // N*4
    int*   esrc  = (int*)  (ws + 66400320);     // (E+N)*4 = 2,600,000
    __bf16* whi1 = (__bf16*)(ws + 69000320);    // 32768*2 = 65536
    __bf16* wlo1 = (__bf16*)(ws + 69065856);    // 65536
    __bf16* whi2 = (__bf16*)(ws + 69131392);    // 8192*2 = 16384
    __bf16* wlo2 = (__bf16*)(ws + 69147776);    // 16384 (ends 69164160)
    // recycled regions:
    float* alphaA = g;                          // (E+N)*4 floats = 10.4MB <= 12.8MB; consumed before gemm2 writes g
    float* alphaB = h1;                         // (E+N) floats; h1 free after aggr1

    const int TOT = E_EDGES + N_NODES;
    const int eb = (TOT + 255) / 256;

    hipMemsetAsync(cursor, 0, N_NODES * sizeof(int), stream);
    hist_kernel<<<eb, 256, 0, stream>>>(ei, cursor);
    scan_kernel<<<1, 1024, 0, stream>>>(cursor, rowp);
    scatter_kernel<<<eb, 256, 0, stream>>>(ei, cursor, esrc);

    pack_w_kernel<F_IN, HC1><<<(F_IN * HC1 + 255) / 256, 256, 0, stream>>>(W1, whi1, wlo1);
    pack_w_kernel<HC1, F_OUT><<<(HC1 * F_OUT + 255) / 256, 256, 0, stream>>>(W2, whi2, wlo2);

    const int gb = (N_NODES + 63) / 64;   // 782 blocks, tail guarded
    gemm_mfma_kernel<F_IN, HC1><<<gb, 256, 0, stream>>>(x, whi1, wlo1, h1);
    al1_kernel<<<N_NODES / 4, 256, 0, stream>>>(h1, a_src1, a_dst1, als1, ald1);
    alpha1_kernel<<<N_NODES / 4, 256, 0, stream>>>(rowp, esrc, als1, ald1, alphaA);
    aggr1_kernel<<<N_NODES / 4, 256, 0, stream>>>(rowp, esrc, alphaA, h1, b1, h2);

    gemm_mfma_kernel<HC1, F_OUT><<<gb, 256, 0, stream>>>(h2, whi2, wlo2, g);
    al2_kernel<<<N_NODES / 4, 256, 0, stream>>>(g, a_src2, a_dst2, als2, ald2);
    alpha2_kernel<<<N_NODES / 4, 256, 0, stream>>>(rowp, esrc, als2, ald2, alphaB);
    aggr2_kernel<<<N_NODES / 4, 256, 0, stream>>>(rowp, esrc, alphaB, g, b2, out);
}

// Round 4
// 275.228 us; speedup vs baseline: 2.0544x; 1.2029x over previous
//
#include <hip/hip_runtime.h>
#include <hip/hip_bf16.h>

#define N_NODES 50000
#define E_EDGES 600000
#define F_IN    256
#define HC1     128   // 4 heads * 32
#define F_OUT   64

typedef __bf16 bf16x8 __attribute__((ext_vector_type(8)));
typedef float  f32x4  __attribute__((ext_vector_type(4)));

// -------------------- CSR build --------------------

__global__ void hist_kernel(const int* __restrict__ ei, int* __restrict__ count) {
    int i = blockIdx.x * blockDim.x + threadIdx.x;
    const int total = E_EDGES + N_NODES;
    if (i >= total) return;
    int d = (i < E_EDGES) ? ei[E_EDGES + i] : (i - E_EDGES);
    atomicAdd(&count[d], 1);
}

__global__ __launch_bounds__(1024) void scan_kernel(int* __restrict__ cursor /*in counts, out offsets*/,
                                                    int* __restrict__ row_ptr) {
    __shared__ int wsum[16];
    __shared__ int running_s;
    int tid = threadIdx.x, lane = tid & 63, w = tid >> 6;
    if (tid == 0) running_s = 0;
    __syncthreads();
    for (int base = 0; base < N_NODES; base += 1024) {
        int i = base + tid;
        int v = (i < N_NODES) ? cursor[i] : 0;
        int s = v;
        #pragma unroll
        for (int d = 1; d < 64; d <<= 1) {
            int t = __shfl_up(s, d);
            if (lane >= d) s += t;
        }
        if (lane == 63) wsum[w] = s;
        __syncthreads();
        if (tid < 16) {
            int ws = wsum[tid];
            #pragma unroll
            for (int d = 1; d < 16; d <<= 1) {
                int t = __shfl_up(ws, d);
                if (tid >= d) ws += t;
            }
            wsum[tid] = ws;  // inclusive scan of wave sums
        }
        __syncthreads();
        int run = running_s;
        int excl = run + (w ? wsum[w - 1] : 0) + s - v;
        if (i < N_NODES) { row_ptr[i] = excl; cursor[i] = excl; }
        int total = wsum[15];
        __syncthreads();   // everyone done reading running_s/wsum
        if (tid == 0) running_s = run + total;
        __syncthreads();
    }
    if (threadIdx.x == 0) row_ptr[N_NODES] = running_s;
}

__global__ void scatter_kernel(const int* __restrict__ ei, int* __restrict__ cursor,
                               int* __restrict__ esrc) {
    int i = blockIdx.x * blockDim.x + threadIdx.x;
    const int total = E_EDGES + N_NODES;
    if (i >= total) return;
    int s, d;
    if (i < E_EDGES) { s = ei[i]; d = ei[E_EDGES + i]; }
    else             { s = d = i - E_EDGES; }
    int pos = atomicAdd(&cursor[d], 1);
    esrc[pos] = s;
}

// -------------------- W pre-pack into MFMA B-fragment order (bf16 hi/lo) ------

// B-frag for 16x16x32: lane l holds k=(l>>4)*8+j, col=l&15 of each [32][16] tile.
// Packed index: ((ct*KT + kt)*64 + l)*8 + j.
template<int KDIM, int NC>
__global__ void pack_w_kernel(const float* __restrict__ W,
                              __bf16* __restrict__ hi, __bf16* __restrict__ lo) {
    constexpr int KT  = KDIM / 32;
    constexpr int LKT = (KT == 8) ? 3 : 2;
    int tid = blockIdx.x * blockDim.x + threadIdx.x;
    if (tid >= KDIM * NC) return;
    int j  = tid & 7;
    int l  = (tid >> 3) & 63;
    int kt = (tid >> 9) & (KT - 1);
    int ct = tid >> (9 + LKT);
    int k   = kt * 32 + (l >> 4) * 8 + j;
    int col = ct * 16 + (l & 15);
    float v = W[k * NC + col];
    __bf16 h = (__bf16)v;
    hi[tid] = h;
    lo[tid] = (__bf16)(v - (float)h);
}

// -------------------- split-bf16 MFMA GEMM + fused al epilogue --------------------
// C[M x NC] = A[M x KDIM] * W; al_s/al_d computed per row in epilogue.
// CBF16: write C as bf16 (layer 1); else fp32 (layer 2).
// NC==128: 4 heads of 32 cols -> al[row*4+h]. NC==64: 1 head -> al[row].
template<int KDIM, int NC, bool CBF16>
__global__ __launch_bounds__(256) void gemm_mfma_kernel(const float* __restrict__ A,
                                                        const __bf16* __restrict__ Whi,
                                                        const __bf16* __restrict__ Wlo,
                                                        const float* __restrict__ a_s,
                                                        const float* __restrict__ a_d,
                                                        void* __restrict__ Cout,
                                                        float* __restrict__ als,
                                                        float* __restrict__ ald) {
    constexpr int KT = KDIM / 32;
    constexpr int CT = NC / 16;
    int tid = threadIdx.x;
    int w = tid >> 6, l = tid & 63;
    int r0 = blockIdx.x * 64 + w * 16;
    int arow = r0 + (l & 15);
    int arc = arow < N_NODES ? arow : N_NODES - 1;   // clamp loads; stores guarded
    int koff = (l >> 4) * 8;
    const float* ap = A + (size_t)arc * KDIM + koff;

    f32x4 acc[CT];
    #pragma unroll
    for (int c = 0; c < CT; ++c) acc[c] = (f32x4){0.f, 0.f, 0.f, 0.f};

    #pragma unroll
    for (int kt = 0; kt < KT; ++kt) {
        float4 x0 = *(const float4*)(ap + kt * 32);
        float4 x1 = *(const float4*)(ap + kt * 32 + 4);
        float xv[8] = {x0.x, x0.y, x0.z, x0.w, x1.x, x1.y, x1.z, x1.w};
        bf16x8 ahi, alo;
        #pragma unroll
        for (int j = 0; j < 8; ++j) {
            __bf16 h = (__bf16)xv[j];
            ahi[j] = h;
            alo[j] = (__bf16)(xv[j] - (float)h);
        }
        #pragma unroll
        for (int c = 0; c < CT; ++c) {
            size_t bidx = ((size_t)(c * KT + kt) * 64 + l) * 8;
            bf16x8 bhi = *(const bf16x8*)(Whi + bidx);
            bf16x8 blo = *(const bf16x8*)(Wlo + bidx);
            acc[c] = __builtin_amdgcn_mfma_f32_16x16x32_bf16(ahi, bhi, acc[c], 0, 0, 0);
            acc[c] = __builtin_amdgcn_mfma_f32_16x16x32_bf16(ahi, blo, acc[c], 0, 0, 0);
            acc[c] = __builtin_amdgcn_mfma_f32_16x16x32_bf16(alo, bhi, acc[c], 0, 0, 0);
        }
    }

    int crow0 = r0 + (l >> 4) * 4;
    int ccol = l & 15;

    // C store
    #pragma unroll
    for (int c = 0; c < CT; ++c) {
        #pragma unroll
        for (int r = 0; r < 4; ++r) {
            int row = crow0 + r;
            if (row < N_NODES) {
                if constexpr (CBF16)
                    ((__bf16*)Cout)[(size_t)row * NC + c * 16 + ccol] = (__bf16)acc[c][r];
                else
                    ((float*)Cout)[(size_t)row * NC + c * 16 + ccol] = acc[c][r];
            }
        }
    }

    // fused attention scalars: per-row dot with a_s / a_d
    float as_c[CT], ad_c[CT];
    #pragma unroll
    for (int c = 0; c < CT; ++c) { as_c[c] = a_s[c * 16 + ccol]; ad_c[c] = a_d[c * 16 + ccol]; }

    #pragma unroll
    for (int r = 0; r < 4; ++r) {
        int row = crow0 + r;
        if constexpr (NC == 128) {
            #pragma unroll
            for (int h = 0; h < 4; ++h) {
                float vs = acc[2 * h][r] * as_c[2 * h] + acc[2 * h + 1][r] * as_c[2 * h + 1];
                float vd = acc[2 * h][r] * ad_c[2 * h] + acc[2 * h + 1][r] * ad_c[2 * h + 1];
                #pragma unroll
                for (int d = 1; d < 16; d <<= 1) {
                    vs += __shfl_xor(vs, d);
                    vd += __shfl_xor(vd, d);
                }
                if (ccol == 0 && row < N_NODES) { als[row * 4 + h] = vs; ald[row * 4 + h] = vd; }
            }
        } else {
            float vs = 0.f, vd = 0.f;
            #pragma unroll
            for (int c = 0; c < CT; ++c) { vs += acc[c][r] * as_c[c]; vd += acc[c][r] * ad_c[c]; }
            #pragma unroll
            for (int d = 1; d < 16; d <<= 1) {
                vs += __shfl_xor(vs, d);
                vd += __shfl_xor(vd, d);
            }
            if (ccol == 0 && row < N_NODES) { als[row] = vs; ald[row] = vd; }
        }
    }
}

__device__ __forceinline__ float lrelu(float x) { return x > 0.f ? x : 0.2f * x; }
__device__ __forceinline__ float bfhi(unsigned v) { return __uint_as_float(v & 0xffff0000u); }
__device__ __forceinline__ float bflo(unsigned v) { return __uint_as_float(v << 16); }

// -------------------- fused online-softmax aggregation --------------------

// layer 1: 1 wave per dst; lane covers cols {2l, 2l+1} (both in head l>>4) of bf16 h1.
// Online no-max softmax: e bounded (+-~15) so exp can't overflow; shift-invariant.
__global__ __launch_bounds__(256) void aggr1_kernel(const int* __restrict__ row_ptr,
                                                    const int* __restrict__ esrc,
                                                    const float* __restrict__ als,
                                                    const float* __restrict__ ald,
                                                    const __bf16* __restrict__ h1b,
                                                    const float* __restrict__ b1,
                                                    float* __restrict__ h2out) {
    int wid = blockIdx.x * 4 + (threadIdx.x >> 6);
    int lane = threadIdx.x & 63;
    int beg = row_ptr[wid], end = row_ptr[wid + 1];
    int hh = lane >> 4;                    // head of cols 2l, 2l+1
    float ad = ald[wid * 4 + hh];
    float acc0 = 0.f, acc1 = 0.f, S = 0.f;
    int j = beg;
    for (; j + 2 <= end; j += 2) {
        int s0 = esrc[j], s1 = esrc[j + 1];
        float p0 = __expf(lrelu(als[s0 * 4 + hh] + ad));
        float p1 = __expf(lrelu(als[s1 * 4 + hh] + ad));
        unsigned v0 = *(const unsigned*)(h1b + (size_t)s0 * HC1 + 2 * lane);
        unsigned v1 = *(const unsigned*)(h1b + (size_t)s1 * HC1 + 2 * lane);
        acc0 += p0 * bflo(v0) + p1 * bflo(v1);
        acc1 += p0 * bfhi(v0) + p1 * bfhi(v1);
        S += p0 + p1;
    }
    if (j < end) {
        int s0 = esrc[j];
        float p0 = __expf(lrelu(als[s0 * 4 + hh] + ad));
        unsigned v0 = *(const unsigned*)(h1b + (size_t)s0 * HC1 + 2 * lane);
        acc0 += p0 * bflo(v0);
        acc1 += p0 * bfhi(v0);
        S += p0;
    }
    float inv = 1.f / S;
    float2 o;
    o.x = lrelu(acc0 * inv + b1[2 * lane]);
    o.y = lrelu(acc1 * inv + b1[2 * lane + 1]);
    *(float2*)(h2out + (size_t)wid * HC1 + 2 * lane) = o;
}

// layer 2: 1 wave per dst; 1 head; fp32 g gather (error lands on output -> keep fp32).
__global__ __launch_bounds__(256) void aggr2_kernel(const int* __restrict__ row_ptr,
                                                    const int* __restrict__ esrc,
                                                    const float* __restrict__ als,
                                                    const float* __restrict__ ald,
                                                    const float* __restrict__ g,
                                                    const float* __restrict__ b2,
                                                    float* __restrict__ out) {
    int wid = blockIdx.x * 4 + (threadIdx.x >> 6);
    int lane = threadIdx.x & 63;
    int beg = row_ptr[wid], end = row_ptr[wid + 1];
    float ad = ald[wid];
    float acc = 0.f, S = 0.f;
    int j = beg;
    for (; j + 2 <= end; j += 2) {
        int s0 = esrc[j], s1 = esrc[j + 1];
        float p0 = __expf(lrelu(als[s0] + ad));
        float p1 = __expf(lrelu(als[s1] + ad));
        float g0 = g[(size_t)s0 * F_OUT + lane];
        float g1 = g[(size_t)s1 * F_OUT + lane];
        acc += p0 * g0 + p1 * g1;
        S += p0 + p1;
    }
    if (j < end) {
        int s0 = esrc[j];
        float p0 = __expf(lrelu(als[s0] + ad));
        acc += p0 * g[(size_t)s0 * F_OUT + lane];
        S += p0;
    }
    out[(size_t)wid * F_OUT + lane] = acc / S + b2[lane];
}

// -------------------- launch --------------------

extern "C" void kernel_launch(void* const* d_in, const int* in_sizes, int n_in,
                              void* d_out, int out_size, void* d_ws, size_t ws_size,
                              hipStream_t stream) {
    const float* x      = (const float*)d_in[0];
    const int*   ei     = (const int*)  d_in[1];
    const float* W1     = (const float*)d_in[2];
    const float* a_src1 = (const float*)d_in[3];
    const float* a_dst1 = (const float*)d_in[4];
    const float* b1     = (const float*)d_in[5];
    const float* W2     = (const float*)d_in[6];
    const float* a_src2 = (const float*)d_in[7];
    const float* a_dst2 = (const float*)d_in[8];
    const float* b2     = (const float*)d_in[9];
    float* out = (float*)d_out;
    char* ws = (char*)d_ws;

    // workspace layout (bytes)
    __bf16* h1b  = (__bf16*)(ws + 0);           // N*128*2 = 12,800,000
    float* h2    = (float*)(ws + 12800000);     // N*128*4 = 25,600,000
    float* g     = (float*)(ws + 38400000);     // N*64*4 = 12,800,000
    float* als1  = (float*)(ws + 51200000);     // N*4*4 = 800,000
    float* ald1  = (float*)(ws + 52000000);     // 800,000
    float* als2  = (float*)(ws + 52800000);     // 200,000
    float* ald2  = (float*)(ws + 53000000);     // 200,000
    int*   rowp  = (int*)  (ws + 53200000);     // (N+1)*4
    int*   cursor= (int*)  (ws + 53400064);     // N*4
    int*   esrc  = (int*)  (ws + 53600064);     // (E+N)*4 = 2,600,000
    __bf16* whi1 = (__bf16*)(ws + 56200064);    // 65,536
    __bf16* wlo1 = (__bf16*)(ws + 56265600);    // 65,536
    __bf16* whi2 = (__bf16*)(ws + 56331136);    // 16,384
    __bf16* wlo2 = (__bf16*)(ws + 56347520);    // 16,384 (end 56,363,904)

    const int TOT = E_EDGES + N_NODES;
    const int eb = (TOT + 255) / 256;

    hipMemsetAsync(cursor, 0, N_NODES * sizeof(int), stream);
    hist_kernel<<<eb, 256, 0, stream>>>(ei, cursor);
    scan_kernel<<<1, 1024, 0, stream>>>(cursor, rowp);
    scatter_kernel<<<eb, 256, 0, stream>>>(ei, cursor, esrc);

    pack_w_kernel<F_IN, HC1><<<(F_IN * HC1 + 255) / 256, 256, 0, stream>>>(W1, whi1, wlo1);
    pack_w_kernel<HC1, F_OUT><<<(HC1 * F_OUT + 255) / 256, 256, 0, stream>>>(W2, whi2, wlo2);

    const int gb = (N_NODES + 63) / 64;   // 782 blocks, tail guarded
    gemm_mfma_kernel<F_IN, HC1, true><<<gb, 256, 0, stream>>>(
        x, whi1, wlo1, a_src1, a_dst1, h1b, als1, ald1);
    aggr1_kernel<<<N_NODES / 4, 256, 0, stream>>>(rowp, esrc, als1, ald1, h1b, b1, h2);

    gemm_mfma_kernel<HC1, F_OUT, false><<<gb, 256, 0, stream>>>(
        h2, whi2, wlo2, a_src2, a_dst2, g, als2, ald2);
    aggr2_kernel<<<N_NODES / 4, 256, 0, stream>>>(rowp, esrc, als2, ald2, g, b2, out);
}

// Round 5
// 265.076 us; speedup vs baseline: 2.1331x; 1.0383x over previous
//
#include <hip/hip_runtime.h>
#include <hip/hip_bf16.h>

#define N_NODES 50000
#define E_EDGES 600000
#define F_IN    256
#define HC1     128   // 4 heads * 32
#define F_OUT   64

typedef __bf16 bf16x8 __attribute__((ext_vector_type(8)));
typedef float  f32x4  __attribute__((ext_vector_type(4)));

// -------------------- CSR build --------------------

__global__ void hist_kernel(const int* __restrict__ ei, int* __restrict__ count) {
    int i = blockIdx.x * blockDim.x + threadIdx.x;
    const int total = E_EDGES + N_NODES;
    if (i >= total) return;
    int d = (i < E_EDGES) ? ei[E_EDGES + i] : (i - E_EDGES);
    atomicAdd(&count[d], 1);
}

__global__ __launch_bounds__(1024) void scan_kernel(int* __restrict__ cursor /*in counts, out offsets*/,
                                                    int* __restrict__ row_ptr) {
    __shared__ int wsum[16];
    __shared__ int running_s;
    int tid = threadIdx.x, lane = tid & 63, w = tid >> 6;
    if (tid == 0) running_s = 0;
    __syncthreads();
    for (int base = 0; base < N_NODES; base += 1024) {
        int i = base + tid;
        int v = (i < N_NODES) ? cursor[i] : 0;
        int s = v;
        #pragma unroll
        for (int d = 1; d < 64; d <<= 1) {
            int t = __shfl_up(s, d);
            if (lane >= d) s += t;
        }
        if (lane == 63) wsum[w] = s;
        __syncthreads();
        if (tid < 16) {
            int ws = wsum[tid];
            #pragma unroll
            for (int d = 1; d < 16; d <<= 1) {
                int t = __shfl_up(ws, d);
                if (tid >= d) ws += t;
            }
            wsum[tid] = ws;  // inclusive scan of wave sums
        }
        __syncthreads();
        int run = running_s;
        int excl = run + (w ? wsum[w - 1] : 0) + s - v;
        if (i < N_NODES) { row_ptr[i] = excl; cursor[i] = excl; }
        int total = wsum[15];
        __syncthreads();   // everyone done reading running_s/wsum
        if (tid == 0) running_s = run + total;
        __syncthreads();
    }
    if (threadIdx.x == 0) row_ptr[N_NODES] = running_s;
}

__global__ void scatter_kernel(const int* __restrict__ ei, int* __restrict__ cursor,
                               int* __restrict__ esrc) {
    int i = blockIdx.x * blockDim.x + threadIdx.x;
    const int total = E_EDGES + N_NODES;
    if (i >= total) return;
    int s, d;
    if (i < E_EDGES) { s = ei[i]; d = ei[E_EDGES + i]; }
    else             { s = d = i - E_EDGES; }
    int pos = atomicAdd(&cursor[d], 1);
    esrc[pos] = s;
}

// -------------------- W pre-pack into MFMA B-fragment order (bf16 hi/lo) ------

// B-frag for 16x16x32: lane l holds k=(l>>4)*8+j, col=l&15 of each [32][16] tile.
// Packed index: ((ct*KT + kt)*64 + l)*8 + j.
template<int KDIM, int NC>
__global__ void pack_w_kernel(const float* __restrict__ W,
                              __bf16* __restrict__ hi, __bf16* __restrict__ lo) {
    constexpr int KT  = KDIM / 32;
    constexpr int LKT = (KT == 8) ? 3 : 2;
    int tid = blockIdx.x * blockDim.x + threadIdx.x;
    if (tid >= KDIM * NC) return;
    int j  = tid & 7;
    int l  = (tid >> 3) & 63;
    int kt = (tid >> 9) & (KT - 1);
    int ct = tid >> (9 + LKT);
    int k   = kt * 32 + (l >> 4) * 8 + j;
    int col = ct * 16 + (l & 15);
    float v = W[k * NC + col];
    __bf16 h = (__bf16)v;
    hi[tid] = h;
    lo[tid] = (__bf16)(v - (float)h);
}

// -------------------- split-bf16 MFMA GEMM + fused al epilogue --------------------
// C[M x NC] = A[M x KDIM] * W; al_s/al_d computed per row in epilogue.
// CBF16: write C as bf16 (layer 1); else fp32 (layer 2).
// CGROUPS: column splits per block (waves specialize). CGROUPS=2: block covers
// 32 rows x NC (wave = 16 rows x NC/2). CGROUPS=1: block covers 64 rows x NC.
// NC==128 w/ CGROUPS=2: each wave holds 2 whole heads -> al wave-local.
// NC==64 w/ CGROUPS=1: single head spans wave -> al wave-local.
template<int KDIM, int NC, bool CBF16, int CGROUPS>
__global__ __launch_bounds__(256) void gemm_mfma_kernel(const float* __restrict__ A,
                                                        const __bf16* __restrict__ Whi,
                                                        const __bf16* __restrict__ Wlo,
                                                        const float* __restrict__ a_s,
                                                        const float* __restrict__ a_d,
                                                        void* __restrict__ Cout,
                                                        float* __restrict__ als,
                                                        float* __restrict__ ald) {
    constexpr int KT  = KDIM / 32;
    constexpr int CT  = NC / 16;          // total col tiles
    constexpr int CTW = CT / CGROUPS;     // col tiles per wave
    constexpr int RPB = (CGROUPS == 2) ? 32 : 64;
    int tid = threadIdx.x;
    int w = tid >> 6, l = tid & 63;
    int rw = (CGROUPS == 2) ? (w & 1) : w;
    int cg = (CGROUPS == 2) ? (w >> 1) : 0;
    int c0 = cg * CTW;                    // col-tile base for this wave
    int r0 = blockIdx.x * RPB + rw * 16;
    int arow = r0 + (l & 15);
    int arc = arow < N_NODES ? arow : N_NODES - 1;   // clamp loads; stores guarded
    int koff = (l >> 4) * 8;
    const float* ap = A + (size_t)arc * KDIM + koff;

    // prefetch ALL of A for this lane up front: one latency exposure, not KT.
    float4 a0[KT], a1[KT];
    #pragma unroll
    for (int kt = 0; kt < KT; ++kt) {
        a0[kt] = *(const float4*)(ap + kt * 32);
        a1[kt] = *(const float4*)(ap + kt * 32 + 4);
    }

    f32x4 acc[CTW];
    #pragma unroll
    for (int c = 0; c < CTW; ++c) acc[c] = (f32x4){0.f, 0.f, 0.f, 0.f};

    #pragma unroll
    for (int kt = 0; kt < KT; ++kt) {
        float xv[8] = {a0[kt].x, a0[kt].y, a0[kt].z, a0[kt].w,
                       a1[kt].x, a1[kt].y, a1[kt].z, a1[kt].w};
        bf16x8 ahi, alo;
        #pragma unroll
        for (int j = 0; j < 8; ++j) {
            __bf16 h = (__bf16)xv[j];
            ahi[j] = h;
            alo[j] = (__bf16)(xv[j] - (float)h);
        }
        #pragma unroll
        for (int c = 0; c < CTW; ++c) {
            size_t bidx = ((size_t)((c0 + c) * KT + kt) * 64 + l) * 8;
            bf16x8 bhi = *(const bf16x8*)(Whi + bidx);
            bf16x8 blo = *(const bf16x8*)(Wlo + bidx);
            acc[c] = __builtin_amdgcn_mfma_f32_16x16x32_bf16(ahi, bhi, acc[c], 0, 0, 0);
            acc[c] = __builtin_amdgcn_mfma_f32_16x16x32_bf16(ahi, blo, acc[c], 0, 0, 0);
            acc[c] = __builtin_amdgcn_mfma_f32_16x16x32_bf16(alo, bhi, acc[c], 0, 0, 0);
        }
    }

    int crow0 = r0 + (l >> 4) * 4;
    int ccol = l & 15;

    // C store
    #pragma unroll
    for (int c = 0; c < CTW; ++c) {
        #pragma unroll
        for (int r = 0; r < 4; ++r) {
            int row = crow0 + r;
            if (row < N_NODES) {
                if constexpr (CBF16)
                    ((__bf16*)Cout)[(size_t)row * NC + (c0 + c) * 16 + ccol] = (__bf16)acc[c][r];
                else
                    ((float*)Cout)[(size_t)row * NC + (c0 + c) * 16 + ccol] = acc[c][r];
            }
        }
    }

    // fused attention scalars: per-row dot with a_s / a_d (wave-local by construction)
    float as_c[CTW], ad_c[CTW];
    #pragma unroll
    for (int c = 0; c < CTW; ++c) {
        as_c[c] = a_s[(c0 + c) * 16 + ccol];
        ad_c[c] = a_d[(c0 + c) * 16 + ccol];
    }

    #pragma unroll
    for (int r = 0; r < 4; ++r) {
        int row = crow0 + r;
        if constexpr (NC == 128) {
            // CTW=4 here: 2 heads per wave, head spans 2 col tiles
            #pragma unroll
            for (int hl = 0; hl < 2; ++hl) {
                int h = cg * 2 + hl;
                float vs = acc[2 * hl][r] * as_c[2 * hl] + acc[2 * hl + 1][r] * as_c[2 * hl + 1];
                float vd = acc[2 * hl][r] * ad_c[2 * hl] + acc[2 * hl + 1][r] * ad_c[2 * hl + 1];
                #pragma unroll
                for (int d = 1; d < 16; d <<= 1) {
                    vs += __shfl_xor(vs, d);
                    vd += __shfl_xor(vd, d);
                }
                if (ccol == 0 && row < N_NODES) { als[row * 4 + h] = vs; ald[row * 4 + h] = vd; }
            }
        } else {
            float vs = 0.f, vd = 0.f;
            #pragma unroll
            for (int c = 0; c < CTW; ++c) { vs += acc[c][r] * as_c[c]; vd += acc[c][r] * ad_c[c]; }
            #pragma unroll
            for (int d = 1; d < 16; d <<= 1) {
                vs += __shfl_xor(vs, d);
                vd += __shfl_xor(vd, d);
            }
            if (ccol == 0 && row < N_NODES) { als[row] = vs; ald[row] = vd; }
        }
    }
}

__device__ __forceinline__ float lrelu(float x) { return x > 0.f ? x : 0.2f * x; }
__device__ __forceinline__ float bfhi(unsigned v) { return __uint_as_float(v & 0xffff0000u); }
__device__ __forceinline__ float bflo(unsigned v) { return __uint_as_float(v << 16); }

// -------------------- fused online-softmax aggregation --------------------

// layer 1: 1 wave per dst; lane covers cols {2l, 2l+1} (both in head l>>4) of bf16 h1.
// Online no-max softmax: e bounded (+-~15) so exp can't overflow; shift-invariant.
__global__ __launch_bounds__(256) void aggr1_kernel(const int* __restrict__ row_ptr,
                                                    const int* __restrict__ esrc,
                                                    const float* __restrict__ als,
                                                    const float* __restrict__ ald,
                                                    const __bf16* __restrict__ h1b,
                                                    const float* __restrict__ b1,
                                                    float* __restrict__ h2out) {
    int wid = blockIdx.x * 4 + (threadIdx.x >> 6);
    int lane = threadIdx.x & 63;
    int beg = row_ptr[wid], end = row_ptr[wid + 1];
    int hh = lane >> 4;                    // head of cols 2l, 2l+1
    float ad = ald[wid * 4 + hh];
    float acc0 = 0.f, acc1 = 0.f, S = 0.f;
    int j = beg;
    for (; j + 2 <= end; j += 2) {
        int s0 = esrc[j], s1 = esrc[j + 1];
        float p0 = __expf(lrelu(als[s0 * 4 + hh] + ad));
        float p1 = __expf(lrelu(als[s1 * 4 + hh] + ad));
        unsigned v0 = *(const unsigned*)(h1b + (size_t)s0 * HC1 + 2 * lane);
        unsigned v1 = *(const unsigned*)(h1b + (size_t)s1 * HC1 + 2 * lane);
        acc0 += p0 * bflo(v0) + p1 * bflo(v1);
        acc1 += p0 * bfhi(v0) + p1 * bfhi(v1);
        S += p0 + p1;
    }
    if (j < end) {
        int s0 = esrc[j];
        float p0 = __expf(lrelu(als[s0 * 4 + hh] + ad));
        unsigned v0 = *(const unsigned*)(h1b + (size_t)s0 * HC1 + 2 * lane);
        acc0 += p0 * bflo(v0);
        acc1 += p0 * bfhi(v0);
        S += p0;
    }
    float inv = 1.f / S;
    float2 o;
    o.x = lrelu(acc0 * inv + b1[2 * lane]);
    o.y = lrelu(acc1 * inv + b1[2 * lane + 1]);
    *(float2*)(h2out + (size_t)wid * HC1 + 2 * lane) = o;
}

// layer 2: 1 wave per dst; 1 head; fp32 g gather (error lands on output -> keep fp32).
__global__ __launch_bounds__(256) void aggr2_kernel(const int* __restrict__ row_ptr,
                                                    const int* __restrict__ esrc,
                                                    const float* __restrict__ als,
                                                    const float* __restrict__ ald,
                                                    const float* __restrict__ g,
                                                    const float* __restrict__ b2,
                                                    float* __restrict__ out) {
    int wid = blockIdx.x * 4 + (threadIdx.x >> 6);
    int lane = threadIdx.x & 63;
    int beg = row_ptr[wid], end = row_ptr[wid + 1];
    float ad = ald[wid];
    float acc = 0.f, S = 0.f;
    int j = beg;
    for (; j + 2 <= end; j += 2) {
        int s0 = esrc[j], s1 = esrc[j + 1];
        float p0 = __expf(lrelu(als[s0] + ad));
        float p1 = __expf(lrelu(als[s1] + ad));
        float g0 = g[(size_t)s0 * F_OUT + lane];
        float g1 = g[(size_t)s1 * F_OUT + lane];
        acc += p0 * g0 + p1 * g1;
        S += p0 + p1;
    }
    if (j < end) {
        int s0 = esrc[j];
        float p0 = __expf(lrelu(als[s0] + ad));
        acc += p0 * g[(size_t)s0 * F_OUT + lane];
        S += p0;
    }
    out[(size_t)wid * F_OUT + lane] = acc / S + b2[lane];
}

// -------------------- launch --------------------

extern "C" void kernel_launch(void* const* d_in, const int* in_sizes, int n_in,
                              void* d_out, int out_size, void* d_ws, size_t ws_size,
                              hipStream_t stream) {
    const float* x      = (const float*)d_in[0];
    const int*   ei     = (const int*)  d_in[1];
    const float* W1     = (const float*)d_in[2];
    const float* a_src1 = (const float*)d_in[3];
    const float* a_dst1 = (const float*)d_in[4];
    const float* b1     = (const float*)d_in[5];
    const float* W2     = (const float*)d_in[6];
    const float* a_src2 = (const float*)d_in[7];
    const float* a_dst2 = (const float*)d_in[8];
    const float* b2     = (const float*)d_in[9];
    float* out = (float*)d_out;
    char* ws = (char*)d_ws;

    // workspace layout (bytes)
    __bf16* h1b  = (__bf16*)(ws + 0);           // N*128*2 = 12,800,000
    float* h2    = (float*)(ws + 12800000);     // N*128*4 = 25,600,000
    float* g     = (float*)(ws + 38400000);     // N*64*4 = 12,800,000
    float* als1  = (float*)(ws + 51200000);     // N*4*4 = 800,000
    float* ald1  = (float*)(ws + 52000000);     // 800,000
    float* als2  = (float*)(ws + 52800000);     // 200,000
    float* ald2  = (float*)(ws + 53000000);     // 200,000
    int*   rowp  = (int*)  (ws + 53200000);     // (N+1)*4
    int*   cursor= (int*)  (ws + 53400064);     // N*4
    int*   esrc  = (int*)  (ws + 53600064);     // (E+N)*4 = 2,600,000
    __bf16* whi1 = (__bf16*)(ws + 56200064);    // 65,536
    __bf16* wlo1 = (__bf16*)(ws + 56265600);    // 65,536
    __bf16* whi2 = (__bf16*)(ws + 56331136);    // 16,384
    __bf16* wlo2 = (__bf16*)(ws + 56347520);    // 16,384 (end 56,363,904)

    const int TOT = E_EDGES + N_NODES;
    const int eb = (TOT + 255) / 256;

    hipMemsetAsync(cursor, 0, N_NODES * sizeof(int), stream);
    hist_kernel<<<eb, 256, 0, stream>>>(ei, cursor);
    scan_kernel<<<1, 1024, 0, stream>>>(cursor, rowp);
    scatter_kernel<<<eb, 256, 0, stream>>>(ei, cursor, esrc);

    pack_w_kernel<F_IN, HC1><<<(F_IN * HC1 + 255) / 256, 256, 0, stream>>>(W1, whi1, wlo1);
    pack_w_kernel<HC1, F_OUT><<<(HC1 * F_OUT + 255) / 256, 256, 0, stream>>>(W2, whi2, wlo2);

    // gemm1: CGROUPS=2 -> 32 rows/block -> 1563 blocks (tail guarded)
    gemm_mfma_kernel<F_IN, HC1, true, 2><<<(N_NODES + 31) / 32, 256, 0, stream>>>(
        x, whi1, wlo1, a_src1, a_dst1, h1b, als1, ald1);
    aggr1_kernel<<<N_NODES / 4, 256, 0, stream>>>(rowp, esrc, als1, ald1, h1b, b1, h2);

    // gemm2: CGROUPS=1 -> 64 rows/block -> 782 blocks
    gemm_mfma_kernel<HC1, F_OUT, false, 1><<<(N_NODES + 63) / 64, 256, 0, stream>>>(
        h2, whi2, wlo2, a_src2, a_dst2, g, als2, ald2);
    aggr2_kernel<<<N_NODES / 4, 256, 0, stream>>>(rowp, esrc, als2, ald2, g, b2, out);
}

// Round 6
// 221.691 us; speedup vs baseline: 2.5505x; 1.1957x over previous
//
#include <hip/hip_runtime.h>
#include <hip/hip_bf16.h>

#define N_NODES 50000
#define E_EDGES 600000
#define F_IN    256
#define HC1     128   // 4 heads * 32
#define F_OUT   64
#define SCAN_BLOCKS 49   // ceil(N_NODES / 1024)

typedef __bf16 bf16x8 __attribute__((ext_vector_type(8)));
typedef float  f32x4  __attribute__((ext_vector_type(4)));

// -------------------- CSR build --------------------

__global__ void hist_kernel(const int* __restrict__ ei, int* __restrict__ count) {
    int i = blockIdx.x * blockDim.x + threadIdx.x;
    const int total = E_EDGES + N_NODES;
    if (i >= total) return;
    int d = (i < E_EDGES) ? ei[E_EDGES + i] : (i - E_EDGES);
    atomicAdd(&count[d], 1);
}

// hierarchical scan, phase 1: block-local exclusive scan + block totals.
__global__ __launch_bounds__(1024) void scan1_kernel(const int* __restrict__ count,
                                                     int* __restrict__ row_ptr,
                                                     int* __restrict__ bsum) {
    __shared__ int wsum[16];
    int tid = threadIdx.x, lane = tid & 63, w = tid >> 6;
    int i = blockIdx.x * 1024 + tid;
    int v = (i < N_NODES) ? count[i] : 0;
    int s = v;
    #pragma unroll
    for (int d = 1; d < 64; d <<= 1) {
        int t = __shfl_up(s, d);
        if (lane >= d) s += t;
    }
    if (lane == 63) wsum[w] = s;
    __syncthreads();
    if (tid < 16) {
        int t = wsum[tid];
        #pragma unroll
        for (int d = 1; d < 16; d <<= 1) {
            int u = __shfl_up(t, d);
            if (tid >= d) t += u;
        }
        wsum[tid] = t;
    }
    __syncthreads();
    int excl = (w ? wsum[w - 1] : 0) + s - v;
    if (i < N_NODES) row_ptr[i] = excl;
    if (tid == 0) bsum[blockIdx.x] = wsum[15];
}

// phase 2: one wave scans the 49 block totals (exclusive); writes grand total.
__global__ void scan2_kernel(int* __restrict__ bsum, int* __restrict__ row_ptr) {
    int lane = threadIdx.x;   // 64 threads
    int v = (lane < SCAN_BLOCKS) ? bsum[lane] : 0;
    int s = v;
    #pragma unroll
    for (int d = 1; d < 64; d <<= 1) {
        int t = __shfl_up(s, d);
        if (lane >= d) s += t;
    }
    if (lane < SCAN_BLOCKS) bsum[lane] = s - v;
    if (lane == 63) row_ptr[N_NODES] = s;
}

// phase 3: add block offsets; init cursor.
__global__ __launch_bounds__(1024) void scan3_kernel(int* __restrict__ row_ptr,
                                                     const int* __restrict__ bsum,
                                                     int* __restrict__ cursor) {
    int i = blockIdx.x * 1024 + threadIdx.x;
    if (i >= N_NODES) return;
    int v = row_ptr[i] + bsum[blockIdx.x];
    row_ptr[i] = v;
    cursor[i] = v;
}

__global__ void scatter_kernel(const int* __restrict__ ei, int* __restrict__ cursor,
                               int* __restrict__ esrc) {
    int i = blockIdx.x * blockDim.x + threadIdx.x;
    const int total = E_EDGES + N_NODES;
    if (i >= total) return;
    int s, d;
    if (i < E_EDGES) { s = ei[i]; d = ei[E_EDGES + i]; }
    else             { s = d = i - E_EDGES; }
    int pos = atomicAdd(&cursor[d], 1);
    esrc[pos] = s;
}

// -------------------- W pre-pack into MFMA B-fragment order (bf16 hi/lo) ------

// B-frag for 16x16x32: lane l holds k=(l>>4)*8+j, col=l&15 of each [32][16] tile.
// Packed index: ((ct*KT + kt)*64 + l)*8 + j.
template<int KDIM, int NC>
__global__ void pack_w_kernel(const float* __restrict__ W,
                              __bf16* __restrict__ hi, __bf16* __restrict__ lo) {
    constexpr int KT  = KDIM / 32;
    constexpr int LKT = (KT == 8) ? 3 : 2;
    int tid = blockIdx.x * blockDim.x + threadIdx.x;
    if (tid >= KDIM * NC) return;
    int j  = tid & 7;
    int l  = (tid >> 3) & 63;
    int kt = (tid >> 9) & (KT - 1);
    int ct = tid >> (9 + LKT);
    int k   = kt * 32 + (l >> 4) * 8 + j;
    int col = ct * 16 + (l & 15);
    float v = W[k * NC + col];
    __bf16 h = (__bf16)v;
    hi[tid] = h;
    lo[tid] = (__bf16)(v - (float)h);
}

// -------------------- split-bf16 MFMA GEMM + fused al epilogue --------------------
// C[M x NC] = A[M x KDIM] * W; al_s/al_d computed per row in epilogue.
// CBF16: write C as bf16 (layer 1); else fp32 (layer 2).
// CGROUPS: column splits per block (waves specialize). CGROUPS=2: block covers
// 32 rows x NC (wave = 16 rows x NC/2). CGROUPS=1: block covers 64 rows x NC.
template<int KDIM, int NC, bool CBF16, int CGROUPS>
__global__ __launch_bounds__(256) void gemm_mfma_kernel(const float* __restrict__ A,
                                                        const __bf16* __restrict__ Whi,
                                                        const __bf16* __restrict__ Wlo,
                                                        const float* __restrict__ a_s,
                                                        const float* __restrict__ a_d,
                                                        void* __restrict__ Cout,
                                                        float* __restrict__ als,
                                                        float* __restrict__ ald) {
    constexpr int KT  = KDIM / 32;
    constexpr int CT  = NC / 16;          // total col tiles
    constexpr int CTW = CT / CGROUPS;     // col tiles per wave
    constexpr int RPB = (CGROUPS == 2) ? 32 : 64;
    int tid = threadIdx.x;
    int w = tid >> 6, l = tid & 63;
    int rw = (CGROUPS == 2) ? (w & 1) : w;
    int cg = (CGROUPS == 2) ? (w >> 1) : 0;
    int c0 = cg * CTW;                    // col-tile base for this wave
    int r0 = blockIdx.x * RPB + rw * 16;
    int arow = r0 + (l & 15);
    int arc = arow < N_NODES ? arow : N_NODES - 1;   // clamp loads; stores guarded
    int koff = (l >> 4) * 8;
    const float* ap = A + (size_t)arc * KDIM + koff;

    // prefetch ALL of A for this lane up front: one latency exposure, not KT.
    float4 a0[KT], a1[KT];
    #pragma unroll
    for (int kt = 0; kt < KT; ++kt) {
        a0[kt] = *(const float4*)(ap + kt * 32);
        a1[kt] = *(const float4*)(ap + kt * 32 + 4);
    }

    f32x4 acc[CTW];
    #pragma unroll
    for (int c = 0; c < CTW; ++c) acc[c] = (f32x4){0.f, 0.f, 0.f, 0.f};

    #pragma unroll
    for (int kt = 0; kt < KT; ++kt) {
        float xv[8] = {a0[kt].x, a0[kt].y, a0[kt].z, a0[kt].w,
                       a1[kt].x, a1[kt].y, a1[kt].z, a1[kt].w};
        bf16x8 ahi, alo;
        #pragma unroll
        for (int j = 0; j < 8; ++j) {
            __bf16 h = (__bf16)xv[j];
            ahi[j] = h;
            alo[j] = (__bf16)(xv[j] - (float)h);
        }
        #pragma unroll
        for (int c = 0; c < CTW; ++c) {
            size_t bidx = ((size_t)((c0 + c) * KT + kt) * 64 + l) * 8;
            bf16x8 bhi = *(const bf16x8*)(Whi + bidx);
            bf16x8 blo = *(const bf16x8*)(Wlo + bidx);
            acc[c] = __builtin_amdgcn_mfma_f32_16x16x32_bf16(ahi, bhi, acc[c], 0, 0, 0);
            acc[c] = __builtin_amdgcn_mfma_f32_16x16x32_bf16(ahi, blo, acc[c], 0, 0, 0);
            acc[c] = __builtin_amdgcn_mfma_f32_16x16x32_bf16(alo, bhi, acc[c], 0, 0, 0);
        }
    }

    int crow0 = r0 + (l >> 4) * 4;
    int ccol = l & 15;

    // C store
    #pragma unroll
    for (int c = 0; c < CTW; ++c) {
        #pragma unroll
        for (int r = 0; r < 4; ++r) {
            int row = crow0 + r;
            if (row < N_NODES) {
                if constexpr (CBF16)
                    ((__bf16*)Cout)[(size_t)row * NC + (c0 + c) * 16 + ccol] = (__bf16)acc[c][r];
                else
                    ((float*)Cout)[(size_t)row * NC + (c0 + c) * 16 + ccol] = acc[c][r];
            }
        }
    }

    // fused attention scalars: per-row dot with a_s / a_d (wave-local by construction)
    float as_c[CTW], ad_c[CTW];
    #pragma unroll
    for (int c = 0; c < CTW; ++c) {
        as_c[c] = a_s[(c0 + c) * 16 + ccol];
        ad_c[c] = a_d[(c0 + c) * 16 + ccol];
    }

    #pragma unroll
    for (int r = 0; r < 4; ++r) {
        int row = crow0 + r;
        if constexpr (NC == 128) {
            // CTW=4 here: 2 heads per wave, head spans 2 col tiles
            #pragma unroll
            for (int hl = 0; hl < 2; ++hl) {
                int h = cg * 2 + hl;
                float vs = acc[2 * hl][r] * as_c[2 * hl] + acc[2 * hl + 1][r] * as_c[2 * hl + 1];
                float vd = acc[2 * hl][r] * ad_c[2 * hl] + acc[2 * hl + 1][r] * ad_c[2 * hl + 1];
                #pragma unroll
                for (int d = 1; d < 16; d <<= 1) {
                    vs += __shfl_xor(vs, d);
                    vd += __shfl_xor(vd, d);
                }
                if (ccol == 0 && row < N_NODES) { als[row * 4 + h] = vs; ald[row * 4 + h] = vd; }
            }
        } else {
            float vs = 0.f, vd = 0.f;
            #pragma unroll
            for (int c = 0; c < CTW; ++c) { vs += acc[c][r] * as_c[c]; vd += acc[c][r] * ad_c[c]; }
            #pragma unroll
            for (int d = 1; d < 16; d <<= 1) {
                vs += __shfl_xor(vs, d);
                vd += __shfl_xor(vd, d);
            }
            if (ccol == 0 && row < N_NODES) { als[row] = vs; ald[row] = vd; }
        }
    }
}

__device__ __forceinline__ float lrelu(float x) { return x > 0.f ? x : 0.2f * x; }
__device__ __forceinline__ float bfhi(unsigned v) { return __uint_as_float(v & 0xffff0000u); }
__device__ __forceinline__ float bflo(unsigned v) { return __uint_as_float(v << 16); }

// -------------------- fused online-softmax aggregation --------------------

// layer 1: 1 wave per dst; lane covers cols {2l, 2l+1} (both in head l>>4) of bf16 h1.
// Online no-max softmax: e bounded (+-~15) so exp can't overflow; shift-invariant.
__global__ __launch_bounds__(256) void aggr1_kernel(const int* __restrict__ row_ptr,
                                                    const int* __restrict__ esrc,
                                                    const float* __restrict__ als,
                                                    const float* __restrict__ ald,
                                                    const __bf16* __restrict__ h1b,
                                                    const float* __restrict__ b1,
                                                    float* __restrict__ h2out) {
    int wid = blockIdx.x * 4 + (threadIdx.x >> 6);
    int lane = threadIdx.x & 63;
    int beg = row_ptr[wid], end = row_ptr[wid + 1];
    int hh = lane >> 4;                    // head of cols 2l, 2l+1
    float ad = ald[wid * 4 + hh];
    float acc0 = 0.f, acc1 = 0.f, S = 0.f;
    int j = beg;
    for (; j + 2 <= end; j += 2) {
        int s0 = esrc[j], s1 = esrc[j + 1];
        float p0 = __expf(lrelu(als[s0 * 4 + hh] + ad));
        float p1 = __expf(lrelu(als[s1 * 4 + hh] + ad));
        unsigned v0 = *(const unsigned*)(h1b + (size_t)s0 * HC1 + 2 * lane);
        unsigned v1 = *(const unsigned*)(h1b + (size_t)s1 * HC1 + 2 * lane);
        acc0 += p0 * bflo(v0) + p1 * bflo(v1);
        acc1 += p0 * bfhi(v0) + p1 * bfhi(v1);
        S += p0 + p1;
    }
    if (j < end) {
        int s0 = esrc[j];
        float p0 = __expf(lrelu(als[s0 * 4 + hh] + ad));
        unsigned v0 = *(const unsigned*)(h1b + (size_t)s0 * HC1 + 2 * lane);
        acc0 += p0 * bflo(v0);
        acc1 += p0 * bfhi(v0);
        S += p0;
    }
    float inv = 1.f / S;
    float2 o;
    o.x = lrelu(acc0 * inv + b1[2 * lane]);
    o.y = lrelu(acc1 * inv + b1[2 * lane + 1]);
    *(float2*)(h2out + (size_t)wid * HC1 + 2 * lane) = o;
}

// layer 2: 1 wave per dst; 1 head; fp32 g gather (error lands on output -> keep fp32).
__global__ __launch_bounds__(256) void aggr2_kernel(const int* __restrict__ row_ptr,
                                                    const int* __restrict__ esrc,
                                                    const float* __restrict__ als,
                                                    const float* __restrict__ ald,
                                                    const float* __restrict__ g,
                                                    const float* __restrict__ b2,
                                                    float* __restrict__ out) {
    int wid = blockIdx.x * 4 + (threadIdx.x >> 6);
    int lane = threadIdx.x & 63;
    int beg = row_ptr[wid], end = row_ptr[wid + 1];
    float ad = ald[wid];
    float acc = 0.f, S = 0.f;
    int j = beg;
    for (; j + 2 <= end; j += 2) {
        int s0 = esrc[j], s1 = esrc[j + 1];
        float p0 = __expf(lrelu(als[s0] + ad));
        float p1 = __expf(lrelu(als[s1] + ad));
        float g0 = g[(size_t)s0 * F_OUT + lane];
        float g1 = g[(size_t)s1 * F_OUT + lane];
        acc += p0 * g0 + p1 * g1;
        S += p0 + p1;
    }
    if (j < end) {
        int s0 = esrc[j];
        float p0 = __expf(lrelu(als[s0] + ad));
        acc += p0 * g[(size_t)s0 * F_OUT + lane];
        S += p0;
    }
    out[(size_t)wid * F_OUT + lane] = acc / S + b2[lane];
}

// -------------------- launch --------------------

extern "C" void kernel_launch(void* const* d_in, const int* in_sizes, int n_in,
                              void* d_out, int out_size, void* d_ws, size_t ws_size,
                              hipStream_t stream) {
    const float* x      = (const float*)d_in[0];
    const int*   ei     = (const int*)  d_in[1];
    const float* W1     = (const float*)d_in[2];
    const float* a_src1 = (const float*)d_in[3];
    const float* a_dst1 = (const float*)d_in[4];
    const float* b1     = (const float*)d_in[5];
    const float* W2     = (const float*)d_in[6];
    const float* a_src2 = (const float*)d_in[7];
    const float* a_dst2 = (const float*)d_in[8];
    const float* b2     = (const float*)d_in[9];
    float* out = (float*)d_out;
    char* ws = (char*)d_ws;

    // workspace layout (bytes)
    __bf16* h1b  = (__bf16*)(ws + 0);           // N*128*2 = 12,800,000
    float* h2    = (float*)(ws + 12800000);     // N*128*4 = 25,600,000
    float* g     = (float*)(ws + 38400000);     // N*64*4 = 12,800,000
    float* als1  = (float*)(ws + 51200000);     // N*4*4 = 800,000
    float* ald1  = (float*)(ws + 52000000);     // 800,000
    float* als2  = (float*)(ws + 52800000);     // 200,000
    float* ald2  = (float*)(ws + 53000000);     // 200,000
    int*   rowp  = (int*)  (ws + 53200000);     // (N+1)*4
    int*   cursor= (int*)  (ws + 53400064);     // N*4
    int*   esrc  = (int*)  (ws + 53600064);     // (E+N)*4 = 2,600,000
    __bf16* whi1 = (__bf16*)(ws + 56200064);    // 65,536
    __bf16* wlo1 = (__bf16*)(ws + 56265600);    // 65,536
    __bf16* whi2 = (__bf16*)(ws + 56331136);    // 16,384
    __bf16* wlo2 = (__bf16*)(ws + 56347520);    // 16,384
    int*   bsum  = (int*)  (ws + 56363904);     // SCAN_BLOCKS*4 (end 56,364,100)

    const int TOT = E_EDGES + N_NODES;
    const int eb = (TOT + 255) / 256;

    hipMemsetAsync(cursor, 0, N_NODES * sizeof(int), stream);
    hist_kernel<<<eb, 256, 0, stream>>>(ei, cursor);
    scan1_kernel<<<SCAN_BLOCKS, 1024, 0, stream>>>(cursor, rowp, bsum);
    scan2_kernel<<<1, 64, 0, stream>>>(bsum, rowp);
    scan3_kernel<<<SCAN_BLOCKS, 1024, 0, stream>>>(rowp, bsum, cursor);
    scatter_kernel<<<eb, 256, 0, stream>>>(ei, cursor, esrc);

    pack_w_kernel<F_IN, HC1><<<(F_IN * HC1 + 255) / 256, 256, 0, stream>>>(W1, whi1, wlo1);
    pack_w_kernel<HC1, F_OUT><<<(HC1 * F_OUT + 255) / 256, 256, 0, stream>>>(W2, whi2, wlo2);

    // gemm1: CGROUPS=2 -> 32 rows/block -> 1563 blocks (tail guarded)
    gemm_mfma_kernel<F_IN, HC1, true, 2><<<(N_NODES + 31) / 32, 256, 0, stream>>>(
        x, whi1, wlo1, a_src1, a_dst1, h1b, als1, ald1);
    aggr1_kernel<<<N_NODES / 4, 256, 0, stream>>>(rowp, esrc, als1, ald1, h1b, b1, h2);

    // gemm2: CGROUPS=1 -> 64 rows/block -> 782 blocks
    gemm_mfma_kernel<HC1, F_OUT, false, 1><<<(N_NODES + 63) / 64, 256, 0, stream>>>(
        h2, whi2, wlo2, a_src2, a_dst2, g, als2, ald2);
    aggr2_kernel<<<N_NODES / 4, 256, 0, stream>>>(rowp, esrc, als2, ald2, g, b2, out);
}

// Round 7
// 202.176 us; speedup vs baseline: 2.7967x; 1.0965x over previous
//
#include <hip/hip_runtime.h>
#include <hip/hip_bf16.h>

#define N_NODES 50000
#define E_EDGES 600000
#define F_IN    256
#define HC1     128   // 4 heads * 32
#define F_OUT   64
#define SCAN_BLOCKS 49   // ceil(N_NODES / 1024)

typedef __bf16 bf16x8 __attribute__((ext_vector_type(8)));
typedef float  f32x4  __attribute__((ext_vector_type(4)));

// -------------------- CSR build --------------------

__global__ void hist_kernel(const int* __restrict__ ei, int* __restrict__ count) {
    int i = blockIdx.x * blockDim.x + threadIdx.x;
    const int total = E_EDGES + N_NODES;
    if (i >= total) return;
    int d = (i < E_EDGES) ? ei[E_EDGES + i] : (i - E_EDGES);
    atomicAdd(&count[d], 1);
}

// hierarchical scan, phase 1: block-local exclusive scan + block totals.
__global__ __launch_bounds__(1024) void scan1_kernel(const int* __restrict__ count,
                                                     int* __restrict__ row_ptr,
                                                     int* __restrict__ bsum) {
    __shared__ int wsum[16];
    int tid = threadIdx.x, lane = tid & 63, w = tid >> 6;
    int i = blockIdx.x * 1024 + tid;
    int v = (i < N_NODES) ? count[i] : 0;
    int s = v;
    #pragma unroll
    for (int d = 1; d < 64; d <<= 1) {
        int t = __shfl_up(s, d);
        if (lane >= d) s += t;
    }
    if (lane == 63) wsum[w] = s;
    __syncthreads();
    if (tid < 16) {
        int t = wsum[tid];
        #pragma unroll
        for (int d = 1; d < 16; d <<= 1) {
            int u = __shfl_up(t, d);
            if (tid >= d) t += u;
        }
        wsum[tid] = t;
    }
    __syncthreads();
    int excl = (w ? wsum[w - 1] : 0) + s - v;
    if (i < N_NODES) row_ptr[i] = excl;
    if (tid == 0) bsum[blockIdx.x] = wsum[15];
}

// phase 2: one wave scans the 49 block totals (exclusive); writes grand total.
__global__ void scan2_kernel(int* __restrict__ bsum, int* __restrict__ row_ptr) {
    int lane = threadIdx.x;   // 64 threads
    int v = (lane < SCAN_BLOCKS) ? bsum[lane] : 0;
    int s = v;
    #pragma unroll
    for (int d = 1; d < 64; d <<= 1) {
        int t = __shfl_up(s, d);
        if (lane >= d) s += t;
    }
    if (lane < SCAN_BLOCKS) bsum[lane] = s - v;
    if (lane == 63) row_ptr[N_NODES] = s;
}

// phase 3: add block offsets; init cursor.
__global__ __launch_bounds__(1024) void scan3_kernel(int* __restrict__ row_ptr,
                                                     const int* __restrict__ bsum,
                                                     int* __restrict__ cursor) {
    int i = blockIdx.x * 1024 + threadIdx.x;
    if (i >= N_NODES) return;
    int v = row_ptr[i] + bsum[blockIdx.x];
    row_ptr[i] = v;
    cursor[i] = v;
}

__global__ void scatter_kernel(const int* __restrict__ ei, int* __restrict__ cursor,
                               int* __restrict__ esrc) {
    int i = blockIdx.x * blockDim.x + threadIdx.x;
    const int total = E_EDGES + N_NODES;
    if (i >= total) return;
    int s, d;
    if (i < E_EDGES) { s = ei[i]; d = ei[E_EDGES + i]; }
    else             { s = d = i - E_EDGES; }
    int pos = atomicAdd(&cursor[d], 1);
    esrc[pos] = s;
}

// -------------------- W pre-pack into MFMA B-fragment order (bf16 hi/lo) ------

template<int KDIM, int NC>
__global__ void pack_w_kernel(const float* __restrict__ W,
                              __bf16* __restrict__ hi, __bf16* __restrict__ lo) {
    constexpr int KT  = KDIM / 32;
    constexpr int LKT = (KT == 8) ? 3 : 2;
    int tid = blockIdx.x * blockDim.x + threadIdx.x;
    if (tid >= KDIM * NC) return;
    int j  = tid & 7;
    int l  = (tid >> 3) & 63;
    int kt = (tid >> 9) & (KT - 1);
    int ct = tid >> (9 + LKT);
    int k   = kt * 32 + (l >> 4) * 8 + j;
    int col = ct * 16 + (l & 15);
    float v = W[k * NC + col];
    __bf16 h = (__bf16)v;
    hi[tid] = h;
    lo[tid] = (__bf16)(v - (float)h);
}

// -------------------- split-bf16 MFMA GEMM + fused al epilogue --------------------

template<int KDIM, int NC, bool CBF16, int CGROUPS>
__global__ __launch_bounds__(256) void gemm_mfma_kernel(const float* __restrict__ A,
                                                        const __bf16* __restrict__ Whi,
                                                        const __bf16* __restrict__ Wlo,
                                                        const float* __restrict__ a_s,
                                                        const float* __restrict__ a_d,
                                                        void* __restrict__ Cout,
                                                        float* __restrict__ als,
                                                        float* __restrict__ ald) {
    constexpr int KT  = KDIM / 32;
    constexpr int CT  = NC / 16;          // total col tiles
    constexpr int CTW = CT / CGROUPS;     // col tiles per wave
    constexpr int RPB = (CGROUPS == 2) ? 32 : 64;
    int tid = threadIdx.x;
    int w = tid >> 6, l = tid & 63;
    int rw = (CGROUPS == 2) ? (w & 1) : w;
    int cg = (CGROUPS == 2) ? (w >> 1) : 0;
    int c0 = cg * CTW;                    // col-tile base for this wave
    int r0 = blockIdx.x * RPB + rw * 16;
    int arow = r0 + (l & 15);
    int arc = arow < N_NODES ? arow : N_NODES - 1;   // clamp loads; stores guarded
    int koff = (l >> 4) * 8;
    const float* ap = A + (size_t)arc * KDIM + koff;

    // prefetch ALL of A for this lane up front: one latency exposure, not KT.
    float4 a0[KT], a1[KT];
    #pragma unroll
    for (int kt = 0; kt < KT; ++kt) {
        a0[kt] = *(const float4*)(ap + kt * 32);
        a1[kt] = *(const float4*)(ap + kt * 32 + 4);
    }

    f32x4 acc[CTW];
    #pragma unroll
    for (int c = 0; c < CTW; ++c) acc[c] = (f32x4){0.f, 0.f, 0.f, 0.f};

    #pragma unroll
    for (int kt = 0; kt < KT; ++kt) {
        float xv[8] = {a0[kt].x, a0[kt].y, a0[kt].z, a0[kt].w,
                       a1[kt].x, a1[kt].y, a1[kt].z, a1[kt].w};
        bf16x8 ahi, alo;
        #pragma unroll
        for (int j = 0; j < 8; ++j) {
            __bf16 h = (__bf16)xv[j];
            ahi[j] = h;
            alo[j] = (__bf16)(xv[j] - (float)h);
        }
        #pragma unroll
        for (int c = 0; c < CTW; ++c) {
            size_t bidx = ((size_t)((c0 + c) * KT + kt) * 64 + l) * 8;
            bf16x8 bhi = *(const bf16x8*)(Whi + bidx);
            bf16x8 blo = *(const bf16x8*)(Wlo + bidx);
            acc[c] = __builtin_amdgcn_mfma_f32_16x16x32_bf16(ahi, bhi, acc[c], 0, 0, 0);
            acc[c] = __builtin_amdgcn_mfma_f32_16x16x32_bf16(ahi, blo, acc[c], 0, 0, 0);
            acc[c] = __builtin_amdgcn_mfma_f32_16x16x32_bf16(alo, bhi, acc[c], 0, 0, 0);
        }
    }

    int crow0 = r0 + (l >> 4) * 4;
    int ccol = l & 15;

    // C store
    #pragma unroll
    for (int c = 0; c < CTW; ++c) {
        #pragma unroll
        for (int r = 0; r < 4; ++r) {
            int row = crow0 + r;
            if (row < N_NODES) {
                if constexpr (CBF16)
                    ((__bf16*)Cout)[(size_t)row * NC + (c0 + c) * 16 + ccol] = (__bf16)acc[c][r];
                else
                    ((float*)Cout)[(size_t)row * NC + (c0 + c) * 16 + ccol] = acc[c][r];
            }
        }
    }

    // fused attention scalars: per-row dot with a_s / a_d (wave-local by construction)
    float as_c[CTW], ad_c[CTW];
    #pragma unroll
    for (int c = 0; c < CTW; ++c) {
        as_c[c] = a_s[(c0 + c) * 16 + ccol];
        ad_c[c] = a_d[(c0 + c) * 16 + ccol];
    }

    #pragma unroll
    for (int r = 0; r < 4; ++r) {
        int row = crow0 + r;
        if constexpr (NC == 128) {
            // CTW=4 here: 2 heads per wave, head spans 2 col tiles
            #pragma unroll
            for (int hl = 0; hl < 2; ++hl) {
                int h = cg * 2 + hl;
                float vs = acc[2 * hl][r] * as_c[2 * hl] + acc[2 * hl + 1][r] * as_c[2 * hl + 1];
                float vd = acc[2 * hl][r] * ad_c[2 * hl] + acc[2 * hl + 1][r] * ad_c[2 * hl + 1];
                #pragma unroll
                for (int d = 1; d < 16; d <<= 1) {
                    vs += __shfl_xor(vs, d);
                    vd += __shfl_xor(vd, d);
                }
                if (ccol == 0 && row < N_NODES) { als[row * 4 + h] = vs; ald[row * 4 + h] = vd; }
            }
        } else {
            float vs = 0.f, vd = 0.f;
            #pragma unroll
            for (int c = 0; c < CTW; ++c) { vs += acc[c][r] * as_c[c]; vd += acc[c][r] * ad_c[c]; }
            #pragma unroll
            for (int d = 1; d < 16; d <<= 1) {
                vs += __shfl_xor(vs, d);
                vd += __shfl_xor(vd, d);
            }
            if (ccol == 0 && row < N_NODES) { als[row] = vs; ald[row] = vd; }
        }
    }
}

__device__ __forceinline__ float lrelu(float x) { return x > 0.f ? x : 0.2f * x; }
__device__ __forceinline__ float bfhi(unsigned v) { return __uint_as_float(v & 0xffff0000u); }
__device__ __forceinline__ float bflo(unsigned v) { return __uint_as_float(v << 16); }

// -------------------- fused online-softmax aggregation (4-edge groups) ----------

// layer 1: 1 wave per dst. 4 groups x 16 lanes; group g handles edge j0+g;
// lane li covers cols li*8..li*8+7 (all in head li>>2) via one 16B load.
// Online no-max softmax (e bounded, shift-invariant).
__global__ __launch_bounds__(256) void aggr1_kernel(const int* __restrict__ row_ptr,
                                                    const int* __restrict__ esrc,
                                                    const float* __restrict__ als,
                                                    const float* __restrict__ ald,
                                                    const __bf16* __restrict__ h1b,
                                                    const float* __restrict__ b1,
                                                    float* __restrict__ h2out) {
    int wid = blockIdx.x * 4 + (threadIdx.x >> 6);
    int lane = threadIdx.x & 63;
    int grp = lane >> 4, li = lane & 15;
    int hh = li >> 2;                       // head of this lane's 8 cols
    int beg = row_ptr[wid], end = row_ptr[wid + 1];
    float ad = ald[wid * 4 + hh];
    float acc[8] = {0,0,0,0,0,0,0,0};
    float S = 0.f;
    for (int j0 = beg; j0 < end; j0 += 4) {
        int j = j0 + grp;
        bool valid = (j < end);
        int s = valid ? esrc[j] : 0;
        float p = valid ? __expf(lrelu(als[s * 4 + hh] + ad)) : 0.f;
        uint4 v = *(const uint4*)(h1b + (size_t)s * HC1 + li * 8);
        acc[0] += p * bflo(v.x); acc[1] += p * bfhi(v.x);
        acc[2] += p * bflo(v.y); acc[3] += p * bfhi(v.y);
        acc[4] += p * bflo(v.z); acc[5] += p * bfhi(v.z);
        acc[6] += p * bflo(v.w); acc[7] += p * bfhi(v.w);
        S += p;
    }
    // reduce across the 4 groups (lane bits 4,5)
    #pragma unroll
    for (int d = 16; d < 64; d <<= 1) {
        #pragma unroll
        for (int c = 0; c < 8; ++c) acc[c] += __shfl_xor(acc[c], d);
        S += __shfl_xor(S, d);
    }
    if (grp == 0) {
        float inv = 1.f / S;
        const float* bp = b1 + li * 8;
        float4 o0, o1;
        o0.x = lrelu(acc[0] * inv + bp[0]);
        o0.y = lrelu(acc[1] * inv + bp[1]);
        o0.z = lrelu(acc[2] * inv + bp[2]);
        o0.w = lrelu(acc[3] * inv + bp[3]);
        o1.x = lrelu(acc[4] * inv + bp[4]);
        o1.y = lrelu(acc[5] * inv + bp[5]);
        o1.z = lrelu(acc[6] * inv + bp[6]);
        o1.w = lrelu(acc[7] * inv + bp[7]);
        float* orow = h2out + (size_t)wid * HC1 + li * 8;
        *(float4*)orow = o0;
        *(float4*)(orow + 4) = o1;
    }
}

// layer 2: 1 wave per dst; 4 groups x 16 lanes; lane li covers cols li*4..li*4+3.
__global__ __launch_bounds__(256) void aggr2_kernel(const int* __restrict__ row_ptr,
                                                    const int* __restrict__ esrc,
                                                    const float* __restrict__ als,
                                                    const float* __restrict__ ald,
                                                    const float* __restrict__ g,
                                                    const float* __restrict__ b2,
                                                    float* __restrict__ out) {
    int wid = blockIdx.x * 4 + (threadIdx.x >> 6);
    int lane = threadIdx.x & 63;
    int grp = lane >> 4, li = lane & 15;
    int beg = row_ptr[wid], end = row_ptr[wid + 1];
    float ad = ald[wid];
    float a0 = 0.f, a1 = 0.f, a2 = 0.f, a3 = 0.f, S = 0.f;
    for (int j0 = beg; j0 < end; j0 += 4) {
        int j = j0 + grp;
        bool valid = (j < end);
        int s = valid ? esrc[j] : 0;
        float p = valid ? __expf(lrelu(als[s] + ad)) : 0.f;
        float4 gv = *(const float4*)(g + (size_t)s * F_OUT + li * 4);
        a0 += p * gv.x; a1 += p * gv.y; a2 += p * gv.z; a3 += p * gv.w;
        S += p;
    }
    #pragma unroll
    for (int d = 16; d < 64; d <<= 1) {
        a0 += __shfl_xor(a0, d); a1 += __shfl_xor(a1, d);
        a2 += __shfl_xor(a2, d); a3 += __shfl_xor(a3, d);
        S += __shfl_xor(S, d);
    }
    if (grp == 0) {
        float inv = 1.f / S;
        const float* bp = b2 + li * 4;
        float4 o;
        o.x = a0 * inv + bp[0];
        o.y = a1 * inv + bp[1];
        o.z = a2 * inv + bp[2];
        o.w = a3 * inv + bp[3];
        *(float4*)(out + (size_t)wid * F_OUT + li * 4) = o;
    }
}

// -------------------- launch --------------------

extern "C" void kernel_launch(void* const* d_in, const int* in_sizes, int n_in,
                              void* d_out, int out_size, void* d_ws, size_t ws_size,
                              hipStream_t stream) {
    const float* x      = (const float*)d_in[0];
    const int*   ei     = (const int*)  d_in[1];
    const float* W1     = (const float*)d_in[2];
    const float* a_src1 = (const float*)d_in[3];
    const float* a_dst1 = (const float*)d_in[4];
    const float* b1     = (const float*)d_in[5];
    const float* W2     = (const float*)d_in[6];
    const float* a_src2 = (const float*)d_in[7];
    const float* a_dst2 = (const float*)d_in[8];
    const float* b2     = (const float*)d_in[9];
    float* out = (float*)d_out;
    char* ws = (char*)d_ws;

    // workspace layout (bytes)
    __bf16* h1b  = (__bf16*)(ws + 0);           // N*128*2 = 12,800,000
    float* h2    = (float*)(ws + 12800000);     // N*128*4 = 25,600,000
    float* g     = (float*)(ws + 38400000);     // N*64*4 = 12,800,000
    float* als1  = (float*)(ws + 51200000);     // N*4*4 = 800,000
    float* ald1  = (float*)(ws + 52000000);     // 800,000
    float* als2  = (float*)(ws + 52800000);     // 200,000
    float* ald2  = (float*)(ws + 53000000);     // 200,000
    int*   rowp  = (int*)  (ws + 53200000);     // (N+1)*4
    int*   cursor= (int*)  (ws + 53400064);     // N*4
    int*   esrc  = (int*)  (ws + 53600064);     // (E+N)*4 = 2,600,000
    __bf16* whi1 = (__bf16*)(ws + 56200064);    // 65,536
    __bf16* wlo1 = (__bf16*)(ws + 56265600);    // 65,536
    __bf16* whi2 = (__bf16*)(ws + 56331136);    // 16,384
    __bf16* wlo2 = (__bf16*)(ws + 56347520);    // 16,384
    int*   bsum  = (int*)  (ws + 56363904);     // SCAN_BLOCKS*4 (end 56,364,100)

    const int TOT = E_EDGES + N_NODES;
    const int eb = (TOT + 255) / 256;

    hipMemsetAsync(cursor, 0, N_NODES * sizeof(int), stream);
    hist_kernel<<<eb, 256, 0, stream>>>(ei, cursor);
    scan1_kernel<<<SCAN_BLOCKS, 1024, 0, stream>>>(cursor, rowp, bsum);
    scan2_kernel<<<1, 64, 0, stream>>>(bsum, rowp);
    scan3_kernel<<<SCAN_BLOCKS, 1024, 0, stream>>>(rowp, bsum, cursor);
    scatter_kernel<<<eb, 256, 0, stream>>>(ei, cursor, esrc);

    pack_w_kernel<F_IN, HC1><<<(F_IN * HC1 + 255) / 256, 256, 0, stream>>>(W1, whi1, wlo1);
    pack_w_kernel<HC1, F_OUT><<<(HC1 * F_OUT + 255) / 256, 256, 0, stream>>>(W2, whi2, wlo2);

    // gemm1: CGROUPS=2 -> 32 rows/block -> 1563 blocks (tail guarded)
    gemm_mfma_kernel<F_IN, HC1, true, 2><<<(N_NODES + 31) / 32, 256, 0, stream>>>(
        x, whi1, wlo1, a_src1, a_dst1, h1b, als1, ald1);
    aggr1_kernel<<<N_NODES / 4, 256, 0, stream>>>(rowp, esrc, als1, ald1, h1b, b1, h2);

    // gemm2: CGROUPS=1 -> 64 rows/block -> 782 blocks
    gemm_mfma_kernel<HC1, F_OUT, false, 1><<<(N_NODES + 63) / 64, 256, 0, stream>>>(
        h2, whi2, wlo2, a_src2, a_dst2, g, als2, ald2);
    aggr2_kernel<<<N_NODES / 4, 256, 0, stream>>>(rowp, esrc, als2, ald2, g, b2, out);
}